// Round 14
// baseline (159.585 us; speedup 1.0000x reference)
//
#include <hip/hip_runtime.h>
#include <math.h>

#define IN_CH 256
#define OUT_CH 64
#define SCHUNK 512  // scan elements per block (needs n <= 256*SCHUNK = 131072)

typedef unsigned short ushort;
typedef unsigned short ushort8 __attribute__((ext_vector_type(8)));
typedef unsigned int uint32x4 __attribute__((ext_vector_type(4)));
typedef __bf16 bf16x8 __attribute__((ext_vector_type(8)));
typedef float f32x4 __attribute__((ext_vector_type(4)));

// ---------- monotonic float<->uint mapping for atomic max ----------
__device__ __forceinline__ unsigned fmap(float f) {
  unsigned u = __float_as_uint(f);
  return (u & 0x80000000u) ? ~u : (u | 0x80000000u);
}
__device__ __forceinline__ float funmap(unsigned u) {
  return (u & 0x80000000u) ? __uint_as_float(u & 0x7fffffffu) : __uint_as_float(~u);
}

__device__ __forceinline__ ushort bf16rne(float v) {
  unsigned u = __float_as_uint(v);
  return (ushort)((u + 0x7FFFu + ((u >> 16) & 1u)) >> 16);
}

// ---------- K0: split W into bf16 hi/lo in MFMA FRAGMENT ORDER ----------
// frag index i = ((ks*4 + ct)*64 + lane)*8 + e  maps to
//   k = ks*32 + (lane>>4)*8 + e ,  col = ct*16 + (lane&15)
__global__ __launch_bounds__(256) void gat_wprep(
    const float* __restrict__ W, ushort* __restrict__ Whi, ushort* __restrict__ Wlo)
{
  int i = blockIdx.x * 256 + threadIdx.x;          // 0..16383
  if (i >= IN_CH * OUT_CH) return;
  int e = i & 7, ln = (i >> 3) & 63, ctks = i >> 9;
  int ct = ctks & 3, ks = ctks >> 2;
  int k = ks * 32 + (ln >> 4) * 8 + e;
  int col = ct * 16 + (ln & 15);
  float v = W[(size_t)k * OUT_CH + col];
  unsigned u = __float_as_uint(v);
  unsigned hb = u & 0xFFFF0000u;                   // truncation split (lo absorbs error)
  Whi[i] = (ushort)(hb >> 16);
  Wlo[i] = bf16rne(v - __uint_as_float(hb));
}

// ---------- K1: Wh = x @ W via split-bf16 MFMA, LDS fragment staging ----------
// Block = 256 thr (4 ct-waves) x 16 rows. Staging: coalesced float4 x-loads ->
// in-reg split -> ds_write into fragment-order LDS -> barrier -> K-loop is pure
// ds_read_b128 (lane-linear, conflict-free) + MFMA. No global load feeds an MFMA.
// Whi in 32 VGPRs/wave; Wlo in 32KB LDS (2048 uint4 — FULL size, R13 bug was [1024]).
// LDS total 48KB -> 3 blocks/CU.
__global__ __launch_bounds__(256, 3) void gat_gemm_mfma(
    const float* __restrict__ x, const ushort* __restrict__ Whi, const ushort* __restrict__ Wlo,
    const float* __restrict__ a_src, const float* __restrict__ a_dst,
    float* __restrict__ Wh, float* __restrict__ e, unsigned* __restrict__ gmax, int n)
{
  __shared__ __align__(16) ushort Af[2 * 8 * 64 * 8];   // 16KB A-frags [hl][ks][lane][e]
  __shared__ uint4  Wl[2048];                           // 32KB Wlo frags (full)
  const int tid = threadIdx.x;
  const int lane = tid & 63;
  const int ct = tid >> 6;             // wave id = column tile
  const int lg = lane >> 4;            // k-pack group
  const int li = lane & 15;            // row (A) / col (B/D)
  const int row0 = blockIdx.x * 16;

  // stage Wlo fragments (coalesced uint4, L2-hot): 2048 uint4 / 256 threads
#pragma unroll
  for (int i = 0; i < 8; ++i) Wl[tid + i * 256] = ((const uint4*)Wlo)[tid + i * 256];

  // my ct's Whi fragments: 32 VGPRs
  bf16x8 wh[8];
#pragma unroll
  for (int ks = 0; ks < 8; ++ks)
    wh[ks] = __builtin_bit_cast(bf16x8, ((const uint4*)Whi)[(ks * 4 + ct) * 64 + lane]);

  // stage x tile: thread = (row = tid>>4, kq = tid&15); 4 passes cover 256 cols
  {
    const int row = tid >> 4, kq = tid & 15;
    int arow = row0 + row; if (arow > n - 1) arow = n - 1;
    const float* __restrict__ xr = x + (size_t)arow * IN_CH;
#pragma unroll
    for (int p = 0; p < 4; ++p) {
      const int c0 = (p * 16 + kq) * 4;
      float4 v = *(const float4*)(xr + c0);
      unsigned b0 = __float_as_uint(v.x), b1 = __float_as_uint(v.y);
      unsigned b2 = __float_as_uint(v.z), b3 = __float_as_uint(v.w);
      // hi = truncation split, packed 2x bf16 per u32
      uint2 hi = { (b1 & 0xFFFF0000u) | (b0 >> 16),
                   (b3 & 0xFFFF0000u) | (b2 >> 16) };
      float l0 = v.x - __uint_as_float(b0 & 0xFFFF0000u);
      float l1 = v.y - __uint_as_float(b1 & 0xFFFF0000u);
      float l2 = v.z - __uint_as_float(b2 & 0xFFFF0000u);
      float l3 = v.w - __uint_as_float(b3 & 0xFFFF0000u);
      uint2 lo = { ((unsigned)bf16rne(l1) << 16) | bf16rne(l0),
                   ((unsigned)bf16rne(l3) << 16) | bf16rne(l2) };
      const int ks = c0 >> 5;
      const int ln = ((c0 >> 3) & 3) * 16 + row;
      const int e0 = c0 & 7;               // 0 or 4
      *(uint2*)&Af[((0 * 8 + ks) * 64 + ln) * 8 + e0] = hi;
      *(uint2*)&Af[((1 * 8 + ks) * 64 + ln) * 8 + e0] = lo;
    }
  }

  const int col = ct * 16 + li;
  const float asd = a_src[col] + a_dst[col];
  __syncthreads();

  // K-loop: pure LDS reads + MFMA
  f32x4 acc = {0.f, 0.f, 0.f, 0.f};
#pragma unroll
  for (int ks = 0; ks < 8; ++ks) {
    bf16x8 ah = __builtin_bit_cast(bf16x8, ((const uint4*)Af)[(0 * 8 + ks) * 64 + lane]);
    bf16x8 al = __builtin_bit_cast(bf16x8, ((const uint4*)Af)[(1 * 8 + ks) * 64 + lane]);
    bf16x8 wl = __builtin_bit_cast(bf16x8, Wl[(ks * 4 + ct) * 64 + lane]);
    acc = __builtin_amdgcn_mfma_f32_16x16x32_bf16(ah, wh[ks], acc, 0, 0, 0);
    acc = __builtin_amdgcn_mfma_f32_16x16x32_bf16(al, wh[ks], acc, 0, 0, 0);
    acc = __builtin_amdgcn_mfma_f32_16x16x32_bf16(ah, wl, acc, 0, 0, 0);
    acc = __builtin_amdgcn_mfma_f32_16x16x32_bf16(al, wl, acc, 0, 0, 0);
  }

  // store Wh (D: row = lg*4 + r, col)
#pragma unroll
  for (int r = 0; r < 4; ++r) {
    int row = row0 + lg * 4 + r;
    if (row < n) Wh[(size_t)row * OUT_CH + col] = acc[r];
  }

  __syncthreads();                      // A-frag reads done; reuse Af as ep
  float* ep = (float*)Af;               // ep[ct*16 + row_local]

  // per-ct e partials: reduce over this wave's 16 cols
#pragma unroll
  for (int r = 0; r < 4; ++r) {
    float pe = acc[r] * asd;
    pe += __shfl_xor(pe, 1); pe += __shfl_xor(pe, 2);
    pe += __shfl_xor(pe, 4); pe += __shfl_xor(pe, 8);
    if (li == 0) ep[ct * 16 + lg * 4 + r] = pe;   // lanes 0,16,32,48
  }
  __syncthreads();

  // lanes 0..15 of wave 0: sum 4 ct partials, write e, track max
  if (tid < 16) {
    int row = row0 + tid;
    float pe = ep[0 * 16 + tid] + ep[1 * 16 + tid] + ep[2 * 16 + tid] + ep[3 * 16 + tid];
    float vmax = -INFINITY;
    if (row < n) { e[row] = pe; vmax = pe; }
    vmax = fmaxf(vmax, __shfl_xor(vmax, 1));
    vmax = fmaxf(vmax, __shfl_xor(vmax, 2));
    vmax = fmaxf(vmax, __shfl_xor(vmax, 4));
    vmax = fmaxf(vmax, __shfl_xor(vmax, 8));
    if (tid == 0) atomicMax(gmax, fmap(vmax));
  }
}

// ---------- K2: detect int64 vs int32 edge_index ----------
__global__ void gat_detect64(const unsigned* __restrict__ eidx, unsigned* __restrict__ flag, int npairs)
{
  unsigned v = 0;
  for (int i = threadIdx.x; i < npairs; i += blockDim.x) v |= eidx[2 * i + 1];
#pragma unroll
  for (int m = 32; m >= 1; m >>= 1) v |= __shfl_xor(v, m);
  if ((threadIdx.x & 63) == 0) atomicOr(flag, v);
}

// ---------- K3: decode edges, count degrees, emit packed rc + rank ----------
// rank = atomicAdd return value -> the scatter needs NO atomics.
template <typename IDX>
__global__ void gat_pass1(
    const void* __restrict__ eidx, const unsigned* __restrict__ flag,
    int* __restrict__ cnt, void* __restrict__ rcbuf, IDX* __restrict__ rank, int E)
{
  int j = blockIdx.x * blockDim.x + threadIdx.x;
  if (j >= E) return;
  int r, c;
  if (*flag == 0) {  // int64 layout
    const long long* p = (const long long*)eidx;
    r = (int)p[j]; c = (int)p[(size_t)E + j];
  } else {           // int32 layout
    const int* p = (const int*)eidx;
    r = p[j]; c = p[(size_t)E + j];
  }
  int rk = atomicAdd(cnt + c, 1);
  if constexpr (sizeof(IDX) == 2) {
    ((unsigned*)rcbuf)[j] = ((unsigned)c << 16) | (unsigned)r;
  } else {
    ((uint2*)rcbuf)[j] = make_uint2((unsigned)r, (unsigned)c);
  }
  rank[j] = (IDX)rk;
}

// ---------- K4a/b/c: hierarchical exclusive scan of cnt -> segp ----------
__global__ __launch_bounds__(256) void scan_partial(
    const int* __restrict__ cnt, int* __restrict__ bsum, int n)
{
  int base = blockIdx.x * SCHUNK;
  int tid = threadIdx.x;
  int s = 0;
  int i0 = base + tid, i1 = base + tid + 256;
  if (i0 < n) s += cnt[i0];
  if (i1 < n) s += cnt[i1];
#pragma unroll
  for (int m = 1; m < 64; m <<= 1) s += __shfl_xor(s, m);
  __shared__ int ws[4];
  if ((tid & 63) == 0) ws[tid >> 6] = s;
  __syncthreads();
  if (tid == 0) bsum[blockIdx.x] = ws[0] + ws[1] + ws[2] + ws[3];
}

__global__ __launch_bounds__(256) void scan_bsum(
    int* __restrict__ bsum, int* __restrict__ segp, int nb, int n, int E)
{
  __shared__ int sh[256];
  int tid = threadIdx.x;
  int v = (tid < nb) ? bsum[tid] : 0;
  sh[tid] = v;
  __syncthreads();
  for (int off = 1; off < 256; off <<= 1) {
    int add = (tid >= off) ? sh[tid - off] : 0;
    __syncthreads();
    sh[tid] += add;
    __syncthreads();
  }
  if (tid < nb) bsum[tid] = sh[tid] - v;   // exclusive block offsets
  if (tid == 0) segp[n] = E;
}

__global__ __launch_bounds__(256) void scan_final(
    const int* __restrict__ cnt, const int* __restrict__ bsum,
    int* __restrict__ segp, int n)
{
  int base = blockIdx.x * SCHUNK;
  int tid = threadIdx.x;
  int i0 = base + 2 * tid, i1 = i0 + 1;
  int c0 = (i0 < n) ? cnt[i0] : 0;
  int c1 = (i1 < n) ? cnt[i1] : 0;
  int ps = c0 + c1;
  __shared__ int sh[256];
  sh[tid] = ps;
  __syncthreads();
  for (int off = 1; off < 256; off <<= 1) {
    int add = (tid >= off) ? sh[tid - off] : 0;
    __syncthreads();
    sh[tid] += add;
    __syncthreads();
  }
  int excl = sh[tid] - ps + bsum[blockIdx.x];
  if (i0 < n) segp[i0] = excl;
  if (i1 < n) segp[i1] = excl + c0;
}

// ---------- K5: atomic-free CSR scatter: perm[segp[c]+rank] = r ----------
template <typename IDX>
__global__ void gat_scatter(
    const void* __restrict__ rcbuf, const IDX* __restrict__ rank,
    const int* __restrict__ segp, IDX* __restrict__ perm, int E)
{
  int j = blockIdx.x * blockDim.x + threadIdx.x;
  if (j >= E) return;
  unsigned r, c;
  if constexpr (sizeof(IDX) == 2) {
    unsigned p = ((const unsigned*)rcbuf)[j];
    r = p & 0xFFFFu; c = p >> 16;
  } else {
    uint2 p = ((const uint2*)rcbuf)[j];
    r = p.x; c = p.y;
  }
  perm[segp[c] + (int)rank[j]] = (IDX)r;
}

// ---------- K6: aggregate + ELU; recompute ev in-loop (1 wave/node, lane=channel) ----------
template <typename IDX>
__global__ __launch_bounds__(256) void gat_aggregate(
    const float* __restrict__ Wh, const float* __restrict__ e,
    const unsigned* __restrict__ gmax, const IDX* __restrict__ perm,
    const int* __restrict__ segp, float* __restrict__ out, int n)
{
  int wave = threadIdx.x >> 6, lane = threadIdx.x & 63;
  int c = blockIdx.x * 4 + wave;
  if (c >= n) return;
  int p0 = segp[c], p1 = segp[c + 1];
  float s = 2.0f * funmap(*gmax);
  float ec = e[c] - s;

  float a0 = 0.f, a1 = 0.f, a2 = 0.f, a3 = 0.f;
  float s0 = 0.f, s1 = 0.f, s2 = 0.f, s3 = 0.f;
  int p = p0;
  for (; p + 4 <= p1; p += 4) {
    unsigned r0 = (unsigned)perm[p],     r1 = (unsigned)perm[p + 1];
    unsigned r2 = (unsigned)perm[p + 2], r3 = (unsigned)perm[p + 3];
    float e0 = e[r0], e1 = e[r1], e2 = e[r2], e3 = e[r3];
    float w0 = Wh[(size_t)r0 * OUT_CH + lane];
    float w1 = Wh[(size_t)r1 * OUT_CH + lane];
    float w2 = Wh[(size_t)r2 * OUT_CH + lane];
    float w3 = Wh[(size_t)r3 * OUT_CH + lane];
    float v0 = __expf(e0 + ec), v1 = __expf(e1 + ec);
    float v2 = __expf(e2 + ec), v3 = __expf(e3 + ec);
    a0 = fmaf(v0, w0, a0); s0 += v0;
    a1 = fmaf(v1, w1, a1); s1 += v1;
    a2 = fmaf(v2, w2, a2); s2 += v2;
    a3 = fmaf(v3, w3, a3); s3 += v3;
  }
  for (; p < p1; ++p) {
    unsigned r = (unsigned)perm[p];
    float v = __expf(e[r] + ec);
    a0 = fmaf(v, Wh[(size_t)r * OUT_CH + lane], a0); s0 += v;
  }
  float acc = (a0 + a1) + (a2 + a3);
  float ssum = (s0 + s1) + (s2 + s3);
  float rden = (p1 > p0) ? 1.0f / ssum : 0.0f;  // empty segment -> elu(0)=0
  acc *= rden;
  out[(size_t)c * OUT_CH + lane] = acc > 0.f ? acc : expm1f(acc);
}

extern "C" void kernel_launch(void* const* d_in, const int* in_sizes, int n_in,
                              void* d_out, int out_size, void* d_ws, size_t ws_size,
                              hipStream_t stream)
{
  const float* x     = (const float*)d_in[0];
  const void*  eidx  = d_in[1];
  const float* W     = (const float*)d_in[2];
  const float* a_src = (const float*)d_in[3];
  const float* a_dst = (const float*)d_in[4];
  float* out = (float*)d_out;

  const int n = in_sizes[0] / IN_CH;   // 50000
  const int E = in_sizes[1] / 2;       // 800000
  const int nb = (n + SCHUNK - 1) / SCHUNK;

  char* ws = (char*)d_ws;
  size_t off = 0;
  auto alloc = [&](size_t bytes) -> void* {
    void* p = ws + off;
    off = (off + bytes + 255) & ~(size_t)255;
    return p;
  };
  float*    Wh     = (float*)alloc((size_t)n * OUT_CH * 4);
  float*    e      = (float*)alloc((size_t)n * 4);
  void*     perm   = alloc((size_t)E * 4);   // ushort or uint, by n
  void*     rcbuf  = alloc((size_t)E * 8);   // packed u32 or uint2, by n
  void*     rank   = alloc((size_t)E * 4);   // u16 or u32, by n
  int*      cnt    = (int*)alloc((size_t)n * 4);
  int*      segp   = (int*)alloc((size_t)(n + 1) * 4);
  int*      bsum   = (int*)alloc((size_t)nb * 4);
  ushort*   Whi    = (ushort*)alloc((size_t)IN_CH * OUT_CH * 2);
  ushort*   Wlo    = (ushort*)alloc((size_t)IN_CH * OUT_CH * 2);
  unsigned* gmax   = (unsigned*)alloc(4);
  unsigned* flag   = (unsigned*)alloc(4);

  hipMemsetAsync(cnt,  0, (size_t)n * 4, stream);
  hipMemsetAsync(gmax, 0, 4, stream);
  hipMemsetAsync(flag, 0, 4, stream);

  gat_wprep<<<(IN_CH * OUT_CH + 255) / 256, 256, 0, stream>>>(W, Whi, Wlo);
  gat_gemm_mfma<<<(n + 15) / 16, 256, 0, stream>>>(x, Whi, Wlo, a_src, a_dst, Wh, e, gmax, n);

  gat_detect64<<<1, 256, 0, stream>>>((const unsigned*)eidx, flag, 8192);
  if (n <= 65536) {
    gat_pass1<ushort><<<(E + 255) / 256, 256, 0, stream>>>(
        eidx, flag, cnt, rcbuf, (ushort*)rank, E);
  } else {
    gat_pass1<unsigned><<<(E + 255) / 256, 256, 0, stream>>>(
        eidx, flag, cnt, rcbuf, (unsigned*)rank, E);
  }
  scan_partial<<<nb, 256, 0, stream>>>(cnt, bsum, n);
  scan_bsum<<<1, 256, 0, stream>>>(bsum, segp, nb, n, E);
  scan_final<<<nb, 256, 0, stream>>>(cnt, bsum, segp, n);
  if (n <= 65536) {
    gat_scatter<ushort><<<(E + 255) / 256, 256, 0, stream>>>(
        rcbuf, (const ushort*)rank, segp, (ushort*)perm, E);
    gat_aggregate<ushort><<<(n + 3) / 4, 256, 0, stream>>>(
        Wh, e, gmax, (const ushort*)perm, segp, out, n);
  } else {
    gat_scatter<unsigned><<<(E + 255) / 256, 256, 0, stream>>>(
        rcbuf, (const unsigned*)rank, segp, (unsigned*)perm, E);
    gat_aggregate<unsigned><<<(n + 3) / 4, 256, 0, stream>>>(
        Wh, e, gmax, (const unsigned*)perm, segp, out, n);
  }
}

// Round 15
// 143.747 us; speedup vs baseline: 1.1102x; 1.1102x over previous
//
#include <hip/hip_runtime.h>
#include <math.h>

#define IN_CH 256
#define OUT_CH 64
#define SCHUNK 512  // scan elements per block (needs n <= 256*SCHUNK = 131072)

typedef unsigned short ushort;
typedef unsigned short ushort8 __attribute__((ext_vector_type(8)));
typedef unsigned int uint32x4 __attribute__((ext_vector_type(4)));
typedef __bf16 bf16x8 __attribute__((ext_vector_type(8)));
typedef float f32x4 __attribute__((ext_vector_type(4)));

// ---------- monotonic float<->uint mapping for atomic max ----------
__device__ __forceinline__ unsigned fmap(float f) {
  unsigned u = __float_as_uint(f);
  return (u & 0x80000000u) ? ~u : (u | 0x80000000u);
}
__device__ __forceinline__ float funmap(unsigned u) {
  return (u & 0x80000000u) ? __uint_as_float(u & 0x7fffffffu) : __uint_as_float(~u);
}

__device__ __forceinline__ ushort bf16rne(float v) {
  unsigned u = __float_as_uint(v);
  return (ushort)((u + 0x7FFFu + ((u >> 16) & 1u)) >> 16);
}

// ---------- K0: split W into bf16 hi/lo in MFMA FRAGMENT ORDER ----------
// frag index i = ((ks*4 + ct)*64 + lane)*8 + e  maps to
//   k = ks*32 + (lane>>4)*8 + e ,  col = ct*16 + (lane&15)
__global__ __launch_bounds__(256) void gat_wprep(
    const float* __restrict__ W, ushort* __restrict__ Whi, ushort* __restrict__ Wlo)
{
  int i = blockIdx.x * 256 + threadIdx.x;          // 0..16383
  if (i >= IN_CH * OUT_CH) return;
  int e = i & 7, ln = (i >> 3) & 63, ctks = i >> 9;
  int ct = ctks & 3, ks = ctks >> 2;
  int k = ks * 32 + (ln >> 4) * 8 + e;
  int col = ct * 16 + (ln & 15);
  float v = W[(size_t)k * OUT_CH + col];
  unsigned u = __float_as_uint(v);
  unsigned hb = u & 0xFFFF0000u;                   // truncation split (lo absorbs error)
  Whi[i] = (ushort)(hb >> 16);
  Wlo[i] = bf16rne(v - __uint_as_float(hb));
}

// ---------- K1: Wh = x @ W via split-bf16 MFMA, 32-row blocks, 2 blocks/CU ----------
// 512 thr = 8 waves = 4 ct x 2 row-groups; 32 rows/block. Staging once per block:
// x -> split frags in LDS (32KB), Wlo frags in LDS (32KB), Whi in 32 VGPRs.
// K-loop = pure ds_read_b128 + MFMA. LDS 64KB -> 2 blocks/CU (16 waves/CU).
__global__ __launch_bounds__(512, 4) void gat_gemm_mfma(
    const float* __restrict__ x, const ushort* __restrict__ Whi, const ushort* __restrict__ Wlo,
    const float* __restrict__ a_src, const float* __restrict__ a_dst,
    float* __restrict__ Wh, float* __restrict__ e, unsigned* __restrict__ gmax, int n)
{
  __shared__ __align__(16) ushort Af[2 * 8 * 2 * 64 * 8];  // 32KB [hl][ks][rg][lane][e]
  __shared__ uint4  Wl[2048];                              // 32KB Wlo frags (full)
  const int tid = threadIdx.x;
  const int lane = tid & 63;
  const int wave = tid >> 6;
  const int ct = wave & 3;             // column tile
  const int rg = wave >> 2;            // row group (0/1)
  const int lg = lane >> 4;            // k-pack group
  const int li = lane & 15;            // row (A) / col (B/D)
  const int row0 = blockIdx.x * 32;

  // stage Wlo fragments (2048 uint4 / 512 threads)
#pragma unroll
  for (int i = 0; i < 4; ++i) Wl[tid + i * 512] = ((const uint4*)Wlo)[tid + i * 512];

  // my ct's Whi fragments: 32 VGPRs (L2-hot)
  bf16x8 wh[8];
#pragma unroll
  for (int ks = 0; ks < 8; ++ks)
    wh[ks] = __builtin_bit_cast(bf16x8, ((const uint4*)Whi)[(ks * 4 + ct) * 64 + lane]);

  // stage x tile: thread = (row = tid>>4 in 0..31, kq = tid&15); 4 passes x float4
  {
    const int row = tid >> 4, kq = tid & 15;
    const int xrg = row >> 4, r16 = row & 15;
    int arow = row0 + row; if (arow > n - 1) arow = n - 1;
    const float* __restrict__ xr = x + (size_t)arow * IN_CH;
#pragma unroll
    for (int p = 0; p < 4; ++p) {
      const int c0 = (p * 16 + kq) * 4;
      float4 v = *(const float4*)(xr + c0);
      unsigned b0 = __float_as_uint(v.x), b1 = __float_as_uint(v.y);
      unsigned b2 = __float_as_uint(v.z), b3 = __float_as_uint(v.w);
      uint2 hi = { (b1 & 0xFFFF0000u) | (b0 >> 16),
                   (b3 & 0xFFFF0000u) | (b2 >> 16) };
      float l0 = v.x - __uint_as_float(b0 & 0xFFFF0000u);
      float l1 = v.y - __uint_as_float(b1 & 0xFFFF0000u);
      float l2 = v.z - __uint_as_float(b2 & 0xFFFF0000u);
      float l3 = v.w - __uint_as_float(b3 & 0xFFFF0000u);
      uint2 lo = { ((unsigned)bf16rne(l1) << 16) | bf16rne(l0),
                   ((unsigned)bf16rne(l3) << 16) | bf16rne(l2) };
      const int ks = c0 >> 5;
      const int ln = ((c0 >> 3) & 3) * 16 + r16;
      const int e0 = c0 & 7;               // 0 or 4
      *(uint2*)&Af[(((0 * 8 + ks) * 2 + xrg) * 64 + ln) * 8 + e0] = hi;
      *(uint2*)&Af[(((1 * 8 + ks) * 2 + xrg) * 64 + ln) * 8 + e0] = lo;
    }
  }

  const int col = ct * 16 + li;
  const float asd = a_src[col] + a_dst[col];
  __syncthreads();

  // K-loop: pure LDS reads + MFMA
  f32x4 acc = {0.f, 0.f, 0.f, 0.f};
#pragma unroll
  for (int ks = 0; ks < 8; ++ks) {
    bf16x8 ah = __builtin_bit_cast(bf16x8, ((const uint4*)Af)[((0 * 8 + ks) * 2 + rg) * 64 + lane]);
    bf16x8 al = __builtin_bit_cast(bf16x8, ((const uint4*)Af)[((1 * 8 + ks) * 2 + rg) * 64 + lane]);
    bf16x8 wl = __builtin_bit_cast(bf16x8, Wl[(ks * 4 + ct) * 64 + lane]);
    acc = __builtin_amdgcn_mfma_f32_16x16x32_bf16(ah, wh[ks], acc, 0, 0, 0);
    acc = __builtin_amdgcn_mfma_f32_16x16x32_bf16(al, wh[ks], acc, 0, 0, 0);
    acc = __builtin_amdgcn_mfma_f32_16x16x32_bf16(ah, wl, acc, 0, 0, 0);
    acc = __builtin_amdgcn_mfma_f32_16x16x32_bf16(al, wl, acc, 0, 0, 0);
  }

  // store Wh (D: row = rg*16 + lg*4 + r, col)
#pragma unroll
  for (int r = 0; r < 4; ++r) {
    int row = row0 + rg * 16 + lg * 4 + r;
    if (row < n) Wh[(size_t)row * OUT_CH + col] = acc[r];
  }

  __syncthreads();                      // A-frag reads done; reuse Af as ep
  float* ep = (float*)Af;               // ep[ct*32 + rg*16 + local]

  // per-ct e partials: reduce over this wave's 16 cols
#pragma unroll
  for (int r = 0; r < 4; ++r) {
    float pe = acc[r] * asd;
    pe += __shfl_xor(pe, 1); pe += __shfl_xor(pe, 2);
    pe += __shfl_xor(pe, 4); pe += __shfl_xor(pe, 8);
    if (li == 0) ep[ct * 32 + rg * 16 + lg * 4 + r] = pe;   // lanes 0,16,32,48
  }
  __syncthreads();

  // lanes 0..31 of waves 0: sum 4 ct partials, write e, track max
  if (tid < 32) {
    int row = row0 + tid;
    float pe = ep[0 * 32 + tid] + ep[1 * 32 + tid] + ep[2 * 32 + tid] + ep[3 * 32 + tid];
    float vmax = -INFINITY;
    if (row < n) { e[row] = pe; vmax = pe; }
    vmax = fmaxf(vmax, __shfl_xor(vmax, 1));
    vmax = fmaxf(vmax, __shfl_xor(vmax, 2));
    vmax = fmaxf(vmax, __shfl_xor(vmax, 4));
    vmax = fmaxf(vmax, __shfl_xor(vmax, 8));
    vmax = fmaxf(vmax, __shfl_xor(vmax, 16));
    if (tid == 0) atomicMax(gmax, fmap(vmax));
  }
}

// ---------- K2: detect int64 vs int32 edge_index ----------
__global__ void gat_detect64(const unsigned* __restrict__ eidx, unsigned* __restrict__ flag, int npairs)
{
  unsigned v = 0;
  for (int i = threadIdx.x; i < npairs; i += blockDim.x) v |= eidx[2 * i + 1];
#pragma unroll
  for (int m = 32; m >= 1; m >>= 1) v |= __shfl_xor(v, m);
  if ((threadIdx.x & 63) == 0) atomicOr(flag, v);
}

// ---------- K3: decode edges, count degrees, emit packed rc + rank ----------
// rank = atomicAdd return value -> the scatter needs NO atomics.
template <typename IDX>
__global__ void gat_pass1(
    const void* __restrict__ eidx, const unsigned* __restrict__ flag,
    int* __restrict__ cnt, void* __restrict__ rcbuf, IDX* __restrict__ rank, int E)
{
  int j = blockIdx.x * blockDim.x + threadIdx.x;
  if (j >= E) return;
  int r, c;
  if (*flag == 0) {  // int64 layout
    const long long* p = (const long long*)eidx;
    r = (int)p[j]; c = (int)p[(size_t)E + j];
  } else {           // int32 layout
    const int* p = (const int*)eidx;
    r = p[j]; c = p[(size_t)E + j];
  }
  int rk = atomicAdd(cnt + c, 1);
  if constexpr (sizeof(IDX) == 2) {
    ((unsigned*)rcbuf)[j] = ((unsigned)c << 16) | (unsigned)r;
  } else {
    ((uint2*)rcbuf)[j] = make_uint2((unsigned)r, (unsigned)c);
  }
  rank[j] = (IDX)rk;
}

// ---------- K4a/b/c: hierarchical exclusive scan of cnt -> segp ----------
__global__ __launch_bounds__(256) void scan_partial(
    const int* __restrict__ cnt, int* __restrict__ bsum, int n)
{
  int base = blockIdx.x * SCHUNK;
  int tid = threadIdx.x;
  int s = 0;
  int i0 = base + tid, i1 = base + tid + 256;
  if (i0 < n) s += cnt[i0];
  if (i1 < n) s += cnt[i1];
#pragma unroll
  for (int m = 1; m < 64; m <<= 1) s += __shfl_xor(s, m);
  __shared__ int ws[4];
  if ((tid & 63) == 0) ws[tid >> 6] = s;
  __syncthreads();
  if (tid == 0) bsum[blockIdx.x] = ws[0] + ws[1] + ws[2] + ws[3];
}

__global__ __launch_bounds__(256) void scan_bsum(
    int* __restrict__ bsum, int* __restrict__ segp, int nb, int n, int E)
{
  __shared__ int sh[256];
  int tid = threadIdx.x;
  int v = (tid < nb) ? bsum[tid] : 0;
  sh[tid] = v;
  __syncthreads();
  for (int off = 1; off < 256; off <<= 1) {
    int add = (tid >= off) ? sh[tid - off] : 0;
    __syncthreads();
    sh[tid] += add;
    __syncthreads();
  }
  if (tid < nb) bsum[tid] = sh[tid] - v;   // exclusive block offsets
  if (tid == 0) segp[n] = E;
}

__global__ __launch_bounds__(256) void scan_final(
    const int* __restrict__ cnt, const int* __restrict__ bsum,
    int* __restrict__ segp, int n)
{
  int base = blockIdx.x * SCHUNK;
  int tid = threadIdx.x;
  int i0 = base + 2 * tid, i1 = i0 + 1;
  int c0 = (i0 < n) ? cnt[i0] : 0;
  int c1 = (i1 < n) ? cnt[i1] : 0;
  int ps = c0 + c1;
  __shared__ int sh[256];
  sh[tid] = ps;
  __syncthreads();
  for (int off = 1; off < 256; off <<= 1) {
    int add = (tid >= off) ? sh[tid - off] : 0;
    __syncthreads();
    sh[tid] += add;
    __syncthreads();
  }
  int excl = sh[tid] - ps + bsum[blockIdx.x];
  if (i0 < n) segp[i0] = excl;
  if (i1 < n) segp[i1] = excl + c0;
}

// ---------- K5: atomic-free CSR scatter: perm[segp[c]+rank] = r ----------
template <typename IDX>
__global__ void gat_scatter(
    const void* __restrict__ rcbuf, const IDX* __restrict__ rank,
    const int* __restrict__ segp, IDX* __restrict__ perm, int E)
{
  int j = blockIdx.x * blockDim.x + threadIdx.x;
  if (j >= E) return;
  unsigned r, c;
  if constexpr (sizeof(IDX) == 2) {
    unsigned p = ((const unsigned*)rcbuf)[j];
    r = p & 0xFFFFu; c = p >> 16;
  } else {
    uint2 p = ((const uint2*)rcbuf)[j];
    r = p.x; c = p.y;
  }
  perm[segp[c] + (int)rank[j]] = (IDX)r;
}

// ---------- K6: aggregate + ELU; recompute ev in-loop (1 wave/node, lane=channel) ----------
template <typename IDX>
__global__ __launch_bounds__(256) void gat_aggregate(
    const float* __restrict__ Wh, const float* __restrict__ e,
    const unsigned* __restrict__ gmax, const IDX* __restrict__ perm,
    const int* __restrict__ segp, float* __restrict__ out, int n)
{
  int wave = threadIdx.x >> 6, lane = threadIdx.x & 63;
  int c = blockIdx.x * 4 + wave;
  if (c >= n) return;
  int p0 = segp[c], p1 = segp[c + 1];
  float s = 2.0f * funmap(*gmax);
  float ec = e[c] - s;

  float a0 = 0.f, a1 = 0.f, a2 = 0.f, a3 = 0.f;
  float s0 = 0.f, s1 = 0.f, s2 = 0.f, s3 = 0.f;
  int p = p0;
  for (; p + 4 <= p1; p += 4) {
    unsigned r0 = (unsigned)perm[p],     r1 = (unsigned)perm[p + 1];
    unsigned r2 = (unsigned)perm[p + 2], r3 = (unsigned)perm[p + 3];
    float e0 = e[r0], e1 = e[r1], e2 = e[r2], e3 = e[r3];
    float w0 = Wh[(size_t)r0 * OUT_CH + lane];
    float w1 = Wh[(size_t)r1 * OUT_CH + lane];
    float w2 = Wh[(size_t)r2 * OUT_CH + lane];
    float w3 = Wh[(size_t)r3 * OUT_CH + lane];
    float v0 = __expf(e0 + ec), v1 = __expf(e1 + ec);
    float v2 = __expf(e2 + ec), v3 = __expf(e3 + ec);
    a0 = fmaf(v0, w0, a0); s0 += v0;
    a1 = fmaf(v1, w1, a1); s1 += v1;
    a2 = fmaf(v2, w2, a2); s2 += v2;
    a3 = fmaf(v3, w3, a3); s3 += v3;
  }
  for (; p < p1; ++p) {
    unsigned r = (unsigned)perm[p];
    float v = __expf(e[r] + ec);
    a0 = fmaf(v, Wh[(size_t)r * OUT_CH + lane], a0); s0 += v;
  }
  float acc = (a0 + a1) + (a2 + a3);
  float ssum = (s0 + s1) + (s2 + s3);
  float rden = (p1 > p0) ? 1.0f / ssum : 0.0f;  // empty segment -> elu(0)=0
  acc *= rden;
  out[(size_t)c * OUT_CH + lane] = acc > 0.f ? acc : expm1f(acc);
}

extern "C" void kernel_launch(void* const* d_in, const int* in_sizes, int n_in,
                              void* d_out, int out_size, void* d_ws, size_t ws_size,
                              hipStream_t stream)
{
  const float* x     = (const float*)d_in[0];
  const void*  eidx  = d_in[1];
  const float* W     = (const float*)d_in[2];
  const float* a_src = (const float*)d_in[3];
  const float* a_dst = (const float*)d_in[4];
  float* out = (float*)d_out;

  const int n = in_sizes[0] / IN_CH;   // 50000
  const int E = in_sizes[1] / 2;       // 800000
  const int nb = (n + SCHUNK - 1) / SCHUNK;

  char* ws = (char*)d_ws;
  size_t off = 0;
  auto alloc = [&](size_t bytes) -> void* {
    void* p = ws + off;
    off = (off + bytes + 255) & ~(size_t)255;
    return p;
  };
  float*    Wh     = (float*)alloc((size_t)n * OUT_CH * 4);
  float*    e      = (float*)alloc((size_t)n * 4);
  void*     perm   = alloc((size_t)E * 4);   // ushort or uint, by n
  void*     rcbuf  = alloc((size_t)E * 8);   // packed u32 or uint2, by n
  void*     rank   = alloc((size_t)E * 4);   // u16 or u32, by n
  int*      cnt    = (int*)alloc((size_t)n * 4);
  int*      segp   = (int*)alloc((size_t)(n + 1) * 4);
  int*      bsum   = (int*)alloc((size_t)nb * 4);
  ushort*   Whi    = (ushort*)alloc((size_t)IN_CH * OUT_CH * 2);
  ushort*   Wlo    = (ushort*)alloc((size_t)IN_CH * OUT_CH * 2);
  unsigned* gmax   = (unsigned*)alloc(4);
  unsigned* flag   = (unsigned*)alloc(4);

  hipMemsetAsync(cnt,  0, (size_t)n * 4, stream);
  hipMemsetAsync(gmax, 0, 4, stream);
  hipMemsetAsync(flag, 0, 4, stream);

  gat_wprep<<<(IN_CH * OUT_CH + 255) / 256, 256, 0, stream>>>(W, Whi, Wlo);
  gat_gemm_mfma<<<(n + 31) / 32, 512, 0, stream>>>(x, Whi, Wlo, a_src, a_dst, Wh, e, gmax, n);

  gat_detect64<<<1, 256, 0, stream>>>((const unsigned*)eidx, flag, 8192);
  if (n <= 65536) {
    gat_pass1<ushort><<<(E + 255) / 256, 256, 0, stream>>>(
        eidx, flag, cnt, rcbuf, (ushort*)rank, E);
  } else {
    gat_pass1<unsigned><<<(E + 255) / 256, 256, 0, stream>>>(
        eidx, flag, cnt, rcbuf, (unsigned*)rank, E);
  }
  scan_partial<<<nb, 256, 0, stream>>>(cnt, bsum, n);
  scan_bsum<<<1, 256, 0, stream>>>(bsum, segp, nb, n, E);
  scan_final<<<nb, 256, 0, stream>>>(cnt, bsum, segp, n);
  if (n <= 65536) {
    gat_scatter<ushort><<<(E + 255) / 256, 256, 0, stream>>>(
        rcbuf, (const ushort*)rank, segp, (ushort*)perm, E);
    gat_aggregate<ushort><<<(n + 3) / 4, 256, 0, stream>>>(
        Wh, e, gmax, (const ushort*)perm, segp, out, n);
  } else {
    gat_scatter<unsigned><<<(E + 255) / 256, 256, 0, stream>>>(
        rcbuf, (const unsigned*)rank, segp, (unsigned*)perm, E);
    gat_aggregate<unsigned><<<(n + 3) / 4, 256, 0, stream>>>(
        Wh, e, gmax, (const unsigned*)perm, segp, out, n);
  }
}

// Round 16
// 137.731 us; speedup vs baseline: 1.1587x; 1.0437x over previous
//
#include <hip/hip_runtime.h>
#include <math.h>

#define IN_CH 256
#define OUT_CH 64
#define SCHUNK 512  // scan elements per block (needs n <= 256*SCHUNK = 131072)

typedef unsigned short ushort;
typedef unsigned short ushort8 __attribute__((ext_vector_type(8)));
typedef unsigned int uint32x4 __attribute__((ext_vector_type(4)));
typedef __bf16 bf16x8 __attribute__((ext_vector_type(8)));
typedef float f32x4 __attribute__((ext_vector_type(4)));

// ---------- monotonic float<->uint mapping for atomic max ----------
__device__ __forceinline__ unsigned fmap(float f) {
  unsigned u = __float_as_uint(f);
  return (u & 0x80000000u) ? ~u : (u | 0x80000000u);
}
__device__ __forceinline__ float funmap(unsigned u) {
  return (u & 0x80000000u) ? __uint_as_float(u & 0x7fffffffu) : __uint_as_float(~u);
}

__device__ __forceinline__ ushort bf16rne(float v) {
  unsigned u = __float_as_uint(v);
  return (ushort)((u + 0x7FFFu + ((u >> 16) & 1u)) >> 16);
}
__device__ __forceinline__ float bf16dec(ushort h) {
  return __uint_as_float((unsigned)h << 16);
}

// ---------- K-clear: one dispatch replaces 3 hipMemsetAsync ----------
__global__ __launch_bounds__(256) void gat_clear(
    int* __restrict__ cnt, unsigned* __restrict__ gmax, unsigned* __restrict__ flag, int n)
{
  int i = blockIdx.x * 256 + threadIdx.x;
  if (i < n) cnt[i] = 0;
  if (i == 0) { *gmax = 0u; *flag = 0u; }
}

// ---------- K0: split W into bf16 hi/lo in MFMA FRAGMENT ORDER ----------
// frag index i = ((ks*4 + ct)*64 + lane)*8 + e  maps to
//   k = ks*32 + (lane>>4)*8 + e ,  col = ct*16 + (lane&15)
__global__ __launch_bounds__(256) void gat_wprep(
    const float* __restrict__ W, ushort* __restrict__ Whi, ushort* __restrict__ Wlo)
{
  int i = blockIdx.x * 256 + threadIdx.x;          // 0..16383
  if (i >= IN_CH * OUT_CH) return;
  int e = i & 7, ln = (i >> 3) & 63, ctks = i >> 9;
  int ct = ctks & 3, ks = ctks >> 2;
  int k = ks * 32 + (ln >> 4) * 8 + e;
  int col = ct * 16 + (ln & 15);
  float v = W[(size_t)k * OUT_CH + col];
  unsigned u = __float_as_uint(v);
  unsigned hb = u & 0xFFFF0000u;                   // truncation split (lo absorbs error)
  Whi[i] = (ushort)(hb >> 16);
  Wlo[i] = bf16rne(v - __uint_as_float(hb));
}

// ---------- K1: Wh = x @ W via split-bf16 MFMA, 32-row blocks, 2 blocks/CU ----------
// 512 thr = 8 waves = 4 ct x 2 row-groups; 32 rows/block. Staging once per block:
// x -> split frags in LDS (32KB), Wlo frags in LDS (32KB), Whi in 32 VGPRs.
// K-loop = pure ds_read_b128 + MFMA. Wh output stored as bf16 (halves gather payload).
__global__ __launch_bounds__(512, 4) void gat_gemm_mfma(
    const float* __restrict__ x, const ushort* __restrict__ Whi, const ushort* __restrict__ Wlo,
    const float* __restrict__ a_src, const float* __restrict__ a_dst,
    ushort* __restrict__ Wh, float* __restrict__ e, unsigned* __restrict__ gmax, int n)
{
  __shared__ __align__(16) ushort Af[2 * 8 * 2 * 64 * 8];  // 32KB [hl][ks][rg][lane][e]
  __shared__ uint4  Wl[2048];                              // 32KB Wlo frags (full)
  const int tid = threadIdx.x;
  const int lane = tid & 63;
  const int wave = tid >> 6;
  const int ct = wave & 3;             // column tile
  const int rg = wave >> 2;            // row group (0/1)
  const int lg = lane >> 4;            // k-pack group
  const int li = lane & 15;            // row (A) / col (B/D)
  const int row0 = blockIdx.x * 32;

  // stage Wlo fragments (2048 uint4 / 512 threads)
#pragma unroll
  for (int i = 0; i < 4; ++i) Wl[tid + i * 512] = ((const uint4*)Wlo)[tid + i * 512];

  // my ct's Whi fragments: 32 VGPRs (L2-hot)
  bf16x8 wh[8];
#pragma unroll
  for (int ks = 0; ks < 8; ++ks)
    wh[ks] = __builtin_bit_cast(bf16x8, ((const uint4*)Whi)[(ks * 4 + ct) * 64 + lane]);

  // stage x tile: thread = (row = tid>>4 in 0..31, kq = tid&15); 4 passes x float4
  {
    const int row = tid >> 4, kq = tid & 15;
    const int xrg = row >> 4, r16 = row & 15;
    int arow = row0 + row; if (arow > n - 1) arow = n - 1;
    const float* __restrict__ xr = x + (size_t)arow * IN_CH;
#pragma unroll
    for (int p = 0; p < 4; ++p) {
      const int c0 = (p * 16 + kq) * 4;
      float4 v = *(const float4*)(xr + c0);
      unsigned b0 = __float_as_uint(v.x), b1 = __float_as_uint(v.y);
      unsigned b2 = __float_as_uint(v.z), b3 = __float_as_uint(v.w);
      uint2 hi = { (b1 & 0xFFFF0000u) | (b0 >> 16),
                   (b3 & 0xFFFF0000u) | (b2 >> 16) };
      float l0 = v.x - __uint_as_float(b0 & 0xFFFF0000u);
      float l1 = v.y - __uint_as_float(b1 & 0xFFFF0000u);
      float l2 = v.z - __uint_as_float(b2 & 0xFFFF0000u);
      float l3 = v.w - __uint_as_float(b3 & 0xFFFF0000u);
      uint2 lo = { ((unsigned)bf16rne(l1) << 16) | bf16rne(l0),
                   ((unsigned)bf16rne(l3) << 16) | bf16rne(l2) };
      const int ks = c0 >> 5;
      const int ln = ((c0 >> 3) & 3) * 16 + r16;
      const int e0 = c0 & 7;               // 0 or 4
      *(uint2*)&Af[(((0 * 8 + ks) * 2 + xrg) * 64 + ln) * 8 + e0] = hi;
      *(uint2*)&Af[(((1 * 8 + ks) * 2 + xrg) * 64 + ln) * 8 + e0] = lo;
    }
  }

  const int col = ct * 16 + li;
  const float asd = a_src[col] + a_dst[col];
  __syncthreads();

  // K-loop: pure LDS reads + MFMA
  f32x4 acc = {0.f, 0.f, 0.f, 0.f};
#pragma unroll
  for (int ks = 0; ks < 8; ++ks) {
    bf16x8 ah = __builtin_bit_cast(bf16x8, ((const uint4*)Af)[((0 * 8 + ks) * 2 + rg) * 64 + lane]);
    bf16x8 al = __builtin_bit_cast(bf16x8, ((const uint4*)Af)[((1 * 8 + ks) * 2 + rg) * 64 + lane]);
    bf16x8 wl = __builtin_bit_cast(bf16x8, Wl[(ks * 4 + ct) * 64 + lane]);
    acc = __builtin_amdgcn_mfma_f32_16x16x32_bf16(ah, wh[ks], acc, 0, 0, 0);
    acc = __builtin_amdgcn_mfma_f32_16x16x32_bf16(al, wh[ks], acc, 0, 0, 0);
    acc = __builtin_amdgcn_mfma_f32_16x16x32_bf16(ah, wl, acc, 0, 0, 0);
    acc = __builtin_amdgcn_mfma_f32_16x16x32_bf16(al, wl, acc, 0, 0, 0);
  }

  // store Wh as bf16 (D: row = rg*16 + lg*4 + r, col)
#pragma unroll
  for (int r = 0; r < 4; ++r) {
    int row = row0 + rg * 16 + lg * 4 + r;
    if (row < n) Wh[(size_t)row * OUT_CH + col] = bf16rne(acc[r]);
  }

  __syncthreads();                      // A-frag reads done; reuse Af as ep
  float* ep = (float*)Af;               // ep[ct*32 + rg*16 + local]

  // per-ct e partials: reduce over this wave's 16 cols
#pragma unroll
  for (int r = 0; r < 4; ++r) {
    float pe = acc[r] * asd;
    pe += __shfl_xor(pe, 1); pe += __shfl_xor(pe, 2);
    pe += __shfl_xor(pe, 4); pe += __shfl_xor(pe, 8);
    if (li == 0) ep[ct * 32 + rg * 16 + lg * 4 + r] = pe;   // lanes 0,16,32,48
  }
  __syncthreads();

  // lanes 0..31 of wave 0: sum 4 ct partials, write e, track max
  if (tid < 32) {
    int row = row0 + tid;
    float pe = ep[0 * 32 + tid] + ep[1 * 32 + tid] + ep[2 * 32 + tid] + ep[3 * 32 + tid];
    float vmax = -INFINITY;
    if (row < n) { e[row] = pe; vmax = pe; }
    vmax = fmaxf(vmax, __shfl_xor(vmax, 1));
    vmax = fmaxf(vmax, __shfl_xor(vmax, 2));
    vmax = fmaxf(vmax, __shfl_xor(vmax, 4));
    vmax = fmaxf(vmax, __shfl_xor(vmax, 8));
    vmax = fmaxf(vmax, __shfl_xor(vmax, 16));
    if (tid == 0) atomicMax(gmax, fmap(vmax));
  }
}

// ---------- K2: detect int64 vs int32 edge_index ----------
__global__ void gat_detect64(const unsigned* __restrict__ eidx, unsigned* __restrict__ flag, int npairs)
{
  unsigned v = 0;
  for (int i = threadIdx.x; i < npairs; i += blockDim.x) v |= eidx[2 * i + 1];
#pragma unroll
  for (int m = 32; m >= 1; m >>= 1) v |= __shfl_xor(v, m);
  if ((threadIdx.x & 63) == 0) atomicOr(flag, v);
}

// ---------- K3: decode edges, count degrees, emit packed rc + rank ----------
// rank = atomicAdd return value -> the scatter needs NO atomics.
template <typename IDX>
__global__ void gat_pass1(
    const void* __restrict__ eidx, const unsigned* __restrict__ flag,
    int* __restrict__ cnt, void* __restrict__ rcbuf, IDX* __restrict__ rank, int E)
{
  int j = blockIdx.x * blockDim.x + threadIdx.x;
  if (j >= E) return;
  int r, c;
  if (*flag == 0) {  // int64 layout
    const long long* p = (const long long*)eidx;
    r = (int)p[j]; c = (int)p[(size_t)E + j];
  } else {           // int32 layout
    const int* p = (const int*)eidx;
    r = p[j]; c = p[(size_t)E + j];
  }
  int rk = atomicAdd(cnt + c, 1);
  if constexpr (sizeof(IDX) == 2) {
    ((unsigned*)rcbuf)[j] = ((unsigned)c << 16) | (unsigned)r;
  } else {
    ((uint2*)rcbuf)[j] = make_uint2((unsigned)r, (unsigned)c);
  }
  rank[j] = (IDX)rk;
}

// ---------- K4a/b/c: hierarchical exclusive scan of cnt -> segp ----------
__global__ __launch_bounds__(256) void scan_partial(
    const int* __restrict__ cnt, int* __restrict__ bsum, int n)
{
  int base = blockIdx.x * SCHUNK;
  int tid = threadIdx.x;
  int s = 0;
  int i0 = base + tid, i1 = base + tid + 256;
  if (i0 < n) s += cnt[i0];
  if (i1 < n) s += cnt[i1];
#pragma unroll
  for (int m = 1; m < 64; m <<= 1) s += __shfl_xor(s, m);
  __shared__ int ws[4];
  if ((tid & 63) == 0) ws[tid >> 6] = s;
  __syncthreads();
  if (tid == 0) bsum[blockIdx.x] = ws[0] + ws[1] + ws[2] + ws[3];
}

__global__ __launch_bounds__(256) void scan_bsum(
    int* __restrict__ bsum, int* __restrict__ segp, int nb, int n, int E)
{
  __shared__ int sh[256];
  int tid = threadIdx.x;
  int v = (tid < nb) ? bsum[tid] : 0;
  sh[tid] = v;
  __syncthreads();
  for (int off = 1; off < 256; off <<= 1) {
    int add = (tid >= off) ? sh[tid - off] : 0;
    __syncthreads();
    sh[tid] += add;
    __syncthreads();
  }
  if (tid < nb) bsum[tid] = sh[tid] - v;   // exclusive block offsets
  if (tid == 0) segp[n] = E;
}

__global__ __launch_bounds__(256) void scan_final(
    const int* __restrict__ cnt, const int* __restrict__ bsum,
    int* __restrict__ segp, int n)
{
  int base = blockIdx.x * SCHUNK;
  int tid = threadIdx.x;
  int i0 = base + 2 * tid, i1 = i0 + 1;
  int c0 = (i0 < n) ? cnt[i0] : 0;
  int c1 = (i1 < n) ? cnt[i1] : 0;
  int ps = c0 + c1;
  __shared__ int sh[256];
  sh[tid] = ps;
  __syncthreads();
  for (int off = 1; off < 256; off <<= 1) {
    int add = (tid >= off) ? sh[tid - off] : 0;
    __syncthreads();
    sh[tid] += add;
    __syncthreads();
  }
  int excl = sh[tid] - ps + bsum[blockIdx.x];
  if (i0 < n) segp[i0] = excl;
  if (i1 < n) segp[i1] = excl + c0;
}

// ---------- K5: atomic-free CSR scatter: perm[segp[c]+rank] = r ----------
template <typename IDX>
__global__ void gat_scatter(
    const void* __restrict__ rcbuf, const IDX* __restrict__ rank,
    const int* __restrict__ segp, IDX* __restrict__ perm, int E)
{
  int j = blockIdx.x * blockDim.x + threadIdx.x;
  if (j >= E) return;
  unsigned r, c;
  if constexpr (sizeof(IDX) == 2) {
    unsigned p = ((const unsigned*)rcbuf)[j];
    r = p & 0xFFFFu; c = p >> 16;
  } else {
    uint2 p = ((const uint2*)rcbuf)[j];
    r = p.x; c = p.y;
  }
  perm[segp[c] + (int)rank[j]] = (IDX)r;
}

// ---------- K6: aggregate + ELU; bf16 Wh gathers, unroll 8 ----------
template <typename IDX>
__global__ __launch_bounds__(256) void gat_aggregate(
    const ushort* __restrict__ Wh, const float* __restrict__ e,
    const unsigned* __restrict__ gmax, const IDX* __restrict__ perm,
    const int* __restrict__ segp, float* __restrict__ out, int n)
{
  int wave = threadIdx.x >> 6, lane = threadIdx.x & 63;
  int c = blockIdx.x * 4 + wave;
  if (c >= n) return;
  int p0 = segp[c], p1 = segp[c + 1];
  float s = 2.0f * funmap(*gmax);
  float ec = e[c] - s;

  float a0 = 0.f, a1 = 0.f, a2 = 0.f, a3 = 0.f;
  float s0 = 0.f, s1 = 0.f, s2 = 0.f, s3 = 0.f;
  int p = p0;
  for (; p + 8 <= p1; p += 8) {
    unsigned r0 = (unsigned)perm[p],     r1 = (unsigned)perm[p + 1];
    unsigned r2 = (unsigned)perm[p + 2], r3 = (unsigned)perm[p + 3];
    unsigned r4 = (unsigned)perm[p + 4], r5 = (unsigned)perm[p + 5];
    unsigned r6 = (unsigned)perm[p + 6], r7 = (unsigned)perm[p + 7];
    float e0 = e[r0], e1 = e[r1], e2 = e[r2], e3 = e[r3];
    float e4 = e[r4], e5 = e[r5], e6 = e[r6], e7 = e[r7];
    float w0 = bf16dec(Wh[(size_t)r0 * OUT_CH + lane]);
    float w1 = bf16dec(Wh[(size_t)r1 * OUT_CH + lane]);
    float w2 = bf16dec(Wh[(size_t)r2 * OUT_CH + lane]);
    float w3 = bf16dec(Wh[(size_t)r3 * OUT_CH + lane]);
    float w4 = bf16dec(Wh[(size_t)r4 * OUT_CH + lane]);
    float w5 = bf16dec(Wh[(size_t)r5 * OUT_CH + lane]);
    float w6 = bf16dec(Wh[(size_t)r6 * OUT_CH + lane]);
    float w7 = bf16dec(Wh[(size_t)r7 * OUT_CH + lane]);
    float v0 = __expf(e0 + ec), v1 = __expf(e1 + ec);
    float v2 = __expf(e2 + ec), v3 = __expf(e3 + ec);
    float v4 = __expf(e4 + ec), v5 = __expf(e5 + ec);
    float v6 = __expf(e6 + ec), v7 = __expf(e7 + ec);
    a0 = fmaf(v0, w0, a0); s0 += v0;
    a1 = fmaf(v1, w1, a1); s1 += v1;
    a2 = fmaf(v2, w2, a2); s2 += v2;
    a3 = fmaf(v3, w3, a3); s3 += v3;
    a0 = fmaf(v4, w4, a0); s0 += v4;
    a1 = fmaf(v5, w5, a1); s1 += v5;
    a2 = fmaf(v6, w6, a2); s2 += v6;
    a3 = fmaf(v7, w7, a3); s3 += v7;
  }
  for (; p < p1; ++p) {
    unsigned r = (unsigned)perm[p];
    float v = __expf(e[r] + ec);
    a0 = fmaf(v, bf16dec(Wh[(size_t)r * OUT_CH + lane]), a0); s0 += v;
  }
  float acc = (a0 + a1) + (a2 + a3);
  float ssum = (s0 + s1) + (s2 + s3);
  float rden = (p1 > p0) ? 1.0f / ssum : 0.0f;  // empty segment -> elu(0)=0
  acc *= rden;
  out[(size_t)c * OUT_CH + lane] = acc > 0.f ? acc : expm1f(acc);
}

extern "C" void kernel_launch(void* const* d_in, const int* in_sizes, int n_in,
                              void* d_out, int out_size, void* d_ws, size_t ws_size,
                              hipStream_t stream)
{
  const float* x     = (const float*)d_in[0];
  const void*  eidx  = d_in[1];
  const float* W     = (const float*)d_in[2];
  const float* a_src = (const float*)d_in[3];
  const float* a_dst = (const float*)d_in[4];
  float* out = (float*)d_out;

  const int n = in_sizes[0] / IN_CH;   // 50000
  const int E = in_sizes[1] / 2;       // 800000
  const int nb = (n + SCHUNK - 1) / SCHUNK;

  char* ws = (char*)d_ws;
  size_t off = 0;
  auto alloc = [&](size_t bytes) -> void* {
    void* p = ws + off;
    off = (off + bytes + 255) & ~(size_t)255;
    return p;
  };
  ushort*   Wh     = (ushort*)alloc((size_t)n * OUT_CH * 2);   // bf16
  float*    e      = (float*)alloc((size_t)n * 4);
  void*     perm   = alloc((size_t)E * 4);   // ushort or uint, by n
  void*     rcbuf  = alloc((size_t)E * 8);   // packed u32 or uint2, by n
  void*     rank   = alloc((size_t)E * 4);   // u16 or u32, by n
  int*      cnt    = (int*)alloc((size_t)n * 4);
  int*      segp   = (int*)alloc((size_t)(n + 1) * 4);
  int*      bsum   = (int*)alloc((size_t)nb * 4);
  ushort*   Whi    = (ushort*)alloc((size_t)IN_CH * OUT_CH * 2);
  ushort*   Wlo    = (ushort*)alloc((size_t)IN_CH * OUT_CH * 2);
  unsigned* gmax   = (unsigned*)alloc(4);
  unsigned* flag   = (unsigned*)alloc(4);

  gat_clear<<<(n + 255) / 256, 256, 0, stream>>>(cnt, gmax, flag, n);
  gat_wprep<<<(IN_CH * OUT_CH + 255) / 256, 256, 0, stream>>>(W, Whi, Wlo);
  gat_gemm_mfma<<<(n + 31) / 32, 512, 0, stream>>>(x, Whi, Wlo, a_src, a_dst, Wh, e, gmax, n);

  gat_detect64<<<1, 256, 0, stream>>>((const unsigned*)eidx, flag, 8192);
  if (n <= 65536) {
    gat_pass1<ushort><<<(E + 255) / 256, 256, 0, stream>>>(
        eidx, flag, cnt, rcbuf, (ushort*)rank, E);
  } else {
    gat_pass1<unsigned><<<(E + 255) / 256, 256, 0, stream>>>(
        eidx, flag, cnt, rcbuf, (unsigned*)rank, E);
  }
  scan_partial<<<nb, 256, 0, stream>>>(cnt, bsum, n);
  scan_bsum<<<1, 256, 0, stream>>>(bsum, segp, nb, n, E);
  scan_final<<<nb, 256, 0, stream>>>(cnt, bsum, segp, n);
  if (n <= 65536) {
    gat_scatter<ushort><<<(E + 255) / 256, 256, 0, stream>>>(
        rcbuf, (const ushort*)rank, segp, (ushort*)perm, E);
    gat_aggregate<ushort><<<(n + 3) / 4, 256, 0, stream>>>(
        Wh, e, gmax, (const ushort*)perm, segp, out, n);
  } else {
    gat_scatter<unsigned><<<(E + 255) / 256, 256, 0, stream>>>(
        rcbuf, (const unsigned*)rank, segp, (unsigned*)perm, E);
    gat_aggregate<unsigned><<<(n + 3) / 4, 256, 0, stream>>>(
        Wh, e, gmax, (const unsigned*)perm, segp, out, n);
  }
}

// Round 17
// 132.402 us; speedup vs baseline: 1.2053x; 1.0402x over previous
//
#include <hip/hip_runtime.h>
#include <math.h>

#define IN_CH 256
#define OUT_CH 64
#define SCHUNK 512  // scan elements per block (needs n <= 256*SCHUNK = 131072)

typedef unsigned short ushort;
typedef unsigned short ushort8 __attribute__((ext_vector_type(8)));
typedef unsigned int uint32x4 __attribute__((ext_vector_type(4)));
typedef __bf16 bf16x8 __attribute__((ext_vector_type(8)));
typedef float f32x4 __attribute__((ext_vector_type(4)));

// ---------- monotonic float<->uint mapping for atomic max ----------
__device__ __forceinline__ unsigned fmap(float f) {
  unsigned u = __float_as_uint(f);
  return (u & 0x80000000u) ? ~u : (u | 0x80000000u);
}
__device__ __forceinline__ float funmap(unsigned u) {
  return (u & 0x80000000u) ? __uint_as_float(u & 0x7fffffffu) : __uint_as_float(~u);
}

__device__ __forceinline__ ushort bf16rne(float v) {
  unsigned u = __float_as_uint(v);
  return (ushort)((u + 0x7FFFu + ((u >> 16) & 1u)) >> 16);
}
__device__ __forceinline__ float bf16dec(ushort h) {
  return __uint_as_float((unsigned)h << 16);
}

// ---------- K0: fused prep — cnt clear + gmax clear + int64 detect + W split ----------
// block 0: detect (block-local reduce, single store -> no clear/OR race)
// blocks 1..64: W split into bf16 hi/lo in MFMA fragment order
// all blocks: cnt clear
__global__ __launch_bounds__(256) void gat_prep(
    const float* __restrict__ W, ushort* __restrict__ Whi, ushort* __restrict__ Wlo,
    const unsigned* __restrict__ eidx, unsigned* __restrict__ flag,
    int* __restrict__ cnt, unsigned* __restrict__ gmax, int n, int npairs)
{
  __shared__ unsigned wsh[4];
  const int b = blockIdx.x, tid = threadIdx.x;
  const int i = b * 256 + tid;
  if (i < n) cnt[i] = 0;
  if (i == 0) *gmax = 0u;
  if (b == 0) {
    unsigned v = 0;
    for (int k = tid; k < npairs; k += 256) v |= eidx[2 * k + 1];
#pragma unroll
    for (int m = 1; m < 64; m <<= 1) v |= __shfl_xor(v, m);
    if ((tid & 63) == 0) wsh[tid >> 6] = v;
    __syncthreads();
    if (tid == 0) *flag = wsh[0] | wsh[1] | wsh[2] | wsh[3];
  } else if (b <= 64) {
    int j = (b - 1) * 256 + tid;                   // 0..16383
    int e = j & 7, ln = (j >> 3) & 63, ctks = j >> 9;
    int ct = ctks & 3, ks = ctks >> 2;
    int k = ks * 32 + (ln >> 4) * 8 + e;
    int col = ct * 16 + (ln & 15);
    float v = W[(size_t)k * OUT_CH + col];
    unsigned u = __float_as_uint(v);
    unsigned hb = u & 0xFFFF0000u;                 // truncation split (lo absorbs error)
    Whi[j] = (ushort)(hb >> 16);
    Wlo[j] = bf16rne(v - __uint_as_float(hb));
  }
}

// ---------- K1: Wh = x @ W via split-bf16 MFMA, 32-row blocks, 2 blocks/CU ----------
// 512 thr = 8 waves = 4 ct x 2 row-groups; 32 rows/block. Staging once per block:
// x -> split frags in LDS (32KB), Wlo frags in LDS (32KB), Whi in 32 VGPRs.
// K-loop = pure ds_read_b128 + MFMA. Wh output stored as bf16 (halves gather payload).
__global__ __launch_bounds__(512, 4) void gat_gemm_mfma(
    const float* __restrict__ x, const ushort* __restrict__ Whi, const ushort* __restrict__ Wlo,
    const float* __restrict__ a_src, const float* __restrict__ a_dst,
    ushort* __restrict__ Wh, float* __restrict__ e, unsigned* __restrict__ gmax, int n)
{
  __shared__ __align__(16) ushort Af[2 * 8 * 2 * 64 * 8];  // 32KB [hl][ks][rg][lane][e]
  __shared__ uint4  Wl[2048];                              // 32KB Wlo frags (full)
  const int tid = threadIdx.x;
  const int lane = tid & 63;
  const int wave = tid >> 6;
  const int ct = wave & 3;             // column tile
  const int rg = wave >> 2;            // row group (0/1)
  const int lg = lane >> 4;            // k-pack group
  const int li = lane & 15;            // row (A) / col (B/D)
  const int row0 = blockIdx.x * 32;

  // stage Wlo fragments (2048 uint4 / 512 threads)
#pragma unroll
  for (int i = 0; i < 4; ++i) Wl[tid + i * 512] = ((const uint4*)Wlo)[tid + i * 512];

  // my ct's Whi fragments: 32 VGPRs (L2-hot)
  bf16x8 wh[8];
#pragma unroll
  for (int ks = 0; ks < 8; ++ks)
    wh[ks] = __builtin_bit_cast(bf16x8, ((const uint4*)Whi)[(ks * 4 + ct) * 64 + lane]);

  // stage x tile: thread = (row = tid>>4 in 0..31, kq = tid&15); 4 passes x float4
  {
    const int row = tid >> 4, kq = tid & 15;
    const int xrg = row >> 4, r16 = row & 15;
    int arow = row0 + row; if (arow > n - 1) arow = n - 1;
    const float* __restrict__ xr = x + (size_t)arow * IN_CH;
#pragma unroll
    for (int p = 0; p < 4; ++p) {
      const int c0 = (p * 16 + kq) * 4;
      float4 v = *(const float4*)(xr + c0);
      unsigned b0 = __float_as_uint(v.x), b1 = __float_as_uint(v.y);
      unsigned b2 = __float_as_uint(v.z), b3 = __float_as_uint(v.w);
      uint2 hi = { (b1 & 0xFFFF0000u) | (b0 >> 16),
                   (b3 & 0xFFFF0000u) | (b2 >> 16) };
      float l0 = v.x - __uint_as_float(b0 & 0xFFFF0000u);
      float l1 = v.y - __uint_as_float(b1 & 0xFFFF0000u);
      float l2 = v.z - __uint_as_float(b2 & 0xFFFF0000u);
      float l3 = v.w - __uint_as_float(b3 & 0xFFFF0000u);
      uint2 lo = { ((unsigned)bf16rne(l1) << 16) | bf16rne(l0),
                   ((unsigned)bf16rne(l3) << 16) | bf16rne(l2) };
      const int ks = c0 >> 5;
      const int ln = ((c0 >> 3) & 3) * 16 + r16;
      const int e0 = c0 & 7;               // 0 or 4
      *(uint2*)&Af[(((0 * 8 + ks) * 2 + xrg) * 64 + ln) * 8 + e0] = hi;
      *(uint2*)&Af[(((1 * 8 + ks) * 2 + xrg) * 64 + ln) * 8 + e0] = lo;
    }
  }

  const int col = ct * 16 + li;
  const float asd = a_src[col] + a_dst[col];
  __syncthreads();

  // K-loop: pure LDS reads + MFMA
  f32x4 acc = {0.f, 0.f, 0.f, 0.f};
#pragma unroll
  for (int ks = 0; ks < 8; ++ks) {
    bf16x8 ah = __builtin_bit_cast(bf16x8, ((const uint4*)Af)[((0 * 8 + ks) * 2 + rg) * 64 + lane]);
    bf16x8 al = __builtin_bit_cast(bf16x8, ((const uint4*)Af)[((1 * 8 + ks) * 2 + rg) * 64 + lane]);
    bf16x8 wl = __builtin_bit_cast(bf16x8, Wl[(ks * 4 + ct) * 64 + lane]);
    acc = __builtin_amdgcn_mfma_f32_16x16x32_bf16(ah, wh[ks], acc, 0, 0, 0);
    acc = __builtin_amdgcn_mfma_f32_16x16x32_bf16(al, wh[ks], acc, 0, 0, 0);
    acc = __builtin_amdgcn_mfma_f32_16x16x32_bf16(ah, wl, acc, 0, 0, 0);
    acc = __builtin_amdgcn_mfma_f32_16x16x32_bf16(al, wl, acc, 0, 0, 0);
  }

  // store Wh as bf16 (D: row = rg*16 + lg*4 + r, col)
#pragma unroll
  for (int r = 0; r < 4; ++r) {
    int row = row0 + rg * 16 + lg * 4 + r;
    if (row < n) Wh[(size_t)row * OUT_CH + col] = bf16rne(acc[r]);
  }

  __syncthreads();                      // A-frag reads done; reuse Af as ep
  float* ep = (float*)Af;               // ep[ct*32 + rg*16 + local]

  // per-ct e partials: reduce over this wave's 16 cols
#pragma unroll
  for (int r = 0; r < 4; ++r) {
    float pe = acc[r] * asd;
    pe += __shfl_xor(pe, 1); pe += __shfl_xor(pe, 2);
    pe += __shfl_xor(pe, 4); pe += __shfl_xor(pe, 8);
    if (li == 0) ep[ct * 32 + rg * 16 + lg * 4 + r] = pe;   // lanes 0,16,32,48
  }
  __syncthreads();

  // lanes 0..31 of wave 0: sum 4 ct partials, write e, track max
  if (tid < 32) {
    int row = row0 + tid;
    float pe = ep[0 * 32 + tid] + ep[1 * 32 + tid] + ep[2 * 32 + tid] + ep[3 * 32 + tid];
    float vmax = -INFINITY;
    if (row < n) { e[row] = pe; vmax = pe; }
    vmax = fmaxf(vmax, __shfl_xor(vmax, 1));
    vmax = fmaxf(vmax, __shfl_xor(vmax, 2));
    vmax = fmaxf(vmax, __shfl_xor(vmax, 4));
    vmax = fmaxf(vmax, __shfl_xor(vmax, 8));
    vmax = fmaxf(vmax, __shfl_xor(vmax, 16));
    if (tid == 0) atomicMax(gmax, fmap(vmax));
  }
}

// ---------- K3: decode edges, count degrees, emit packed rc + rank ----------
// rank = atomicAdd return value -> the scatter needs NO atomics.
template <typename IDX>
__global__ void gat_pass1(
    const void* __restrict__ eidx, const unsigned* __restrict__ flag,
    int* __restrict__ cnt, void* __restrict__ rcbuf, IDX* __restrict__ rank, int E)
{
  int j = blockIdx.x * blockDim.x + threadIdx.x;
  if (j >= E) return;
  int r, c;
  if (*flag == 0) {  // int64 layout
    const long long* p = (const long long*)eidx;
    r = (int)p[j]; c = (int)p[(size_t)E + j];
  } else {           // int32 layout
    const int* p = (const int*)eidx;
    r = p[j]; c = p[(size_t)E + j];
  }
  int rk = atomicAdd(cnt + c, 1);
  if constexpr (sizeof(IDX) == 2) {
    ((unsigned*)rcbuf)[j] = ((unsigned)c << 16) | (unsigned)r;
  } else {
    ((uint2*)rcbuf)[j] = make_uint2((unsigned)r, (unsigned)c);
  }
  rank[j] = (IDX)rk;
}

// ---------- K4a/b/c: hierarchical exclusive scan of cnt -> segp ----------
__global__ __launch_bounds__(256) void scan_partial(
    const int* __restrict__ cnt, int* __restrict__ bsum, int n)
{
  int base = blockIdx.x * SCHUNK;
  int tid = threadIdx.x;
  int s = 0;
  int i0 = base + tid, i1 = base + tid + 256;
  if (i0 < n) s += cnt[i0];
  if (i1 < n) s += cnt[i1];
#pragma unroll
  for (int m = 1; m < 64; m <<= 1) s += __shfl_xor(s, m);
  __shared__ int ws[4];
  if ((tid & 63) == 0) ws[tid >> 6] = s;
  __syncthreads();
  if (tid == 0) bsum[blockIdx.x] = ws[0] + ws[1] + ws[2] + ws[3];
}

__global__ __launch_bounds__(256) void scan_bsum(
    int* __restrict__ bsum, int* __restrict__ segp, int nb, int n, int E)
{
  __shared__ int sh[256];
  int tid = threadIdx.x;
  int v = (tid < nb) ? bsum[tid] : 0;
  sh[tid] = v;
  __syncthreads();
  for (int off = 1; off < 256; off <<= 1) {
    int add = (tid >= off) ? sh[tid - off] : 0;
    __syncthreads();
    sh[tid] += add;
    __syncthreads();
  }
  if (tid < nb) bsum[tid] = sh[tid] - v;   // exclusive block offsets
  if (tid == 0) segp[n] = E;
}

__global__ __launch_bounds__(256) void scan_final(
    const int* __restrict__ cnt, const int* __restrict__ bsum,
    int* __restrict__ segp, int n)
{
  int base = blockIdx.x * SCHUNK;
  int tid = threadIdx.x;
  int i0 = base + 2 * tid, i1 = i0 + 1;
  int c0 = (i0 < n) ? cnt[i0] : 0;
  int c1 = (i1 < n) ? cnt[i1] : 0;
  int ps = c0 + c1;
  __shared__ int sh[256];
  sh[tid] = ps;
  __syncthreads();
  for (int off = 1; off < 256; off <<= 1) {
    int add = (tid >= off) ? sh[tid - off] : 0;
    __syncthreads();
    sh[tid] += add;
    __syncthreads();
  }
  int excl = sh[tid] - ps + bsum[blockIdx.x];
  if (i0 < n) segp[i0] = excl;
  if (i1 < n) segp[i1] = excl + c0;
}

// ---------- K5: atomic-free CSR scatter: perm[segp[c]+rank] = r ----------
template <typename IDX>
__global__ void gat_scatter(
    const void* __restrict__ rcbuf, const IDX* __restrict__ rank,
    const int* __restrict__ segp, IDX* __restrict__ perm, int E)
{
  int j = blockIdx.x * blockDim.x + threadIdx.x;
  if (j >= E) return;
  unsigned r, c;
  if constexpr (sizeof(IDX) == 2) {
    unsigned p = ((const unsigned*)rcbuf)[j];
    r = p & 0xFFFFu; c = p >> 16;
  } else {
    uint2 p = ((const uint2*)rcbuf)[j];
    r = p.x; c = p.y;
  }
  perm[segp[c] + (int)rank[j]] = (IDX)r;
}

// ---------- K6: aggregate + ELU; bf16 Wh gathers, masked unroll 16 (no serial tail) ----------
template <typename IDX>
__global__ __launch_bounds__(256) void gat_aggregate(
    const ushort* __restrict__ Wh, const float* __restrict__ e,
    const unsigned* __restrict__ gmax, const IDX* __restrict__ perm,
    const int* __restrict__ segp, float* __restrict__ out, int n)
{
  int wave = threadIdx.x >> 6, lane = threadIdx.x & 63;
  int c = blockIdx.x * 4 + wave;
  if (c >= n) return;
  int p0 = segp[c], p1 = segp[c + 1];
  float s = 2.0f * funmap(*gmax);
  float ec = e[c] - s;

  float a0 = 0.f, a1 = 0.f, a2 = 0.f, a3 = 0.f;
  float s0 = 0.f, s1 = 0.f, s2 = 0.f, s3 = 0.f;
  if (p1 > p0) {
    for (int p = p0; p < p1; p += 16) {
      // 16 independent gather chains; tail lanes clamped + zero-masked
      unsigned rr[16]; float ee[16], ww[16], mk[16];
#pragma unroll
      for (int i = 0; i < 16; ++i) {
        int q = p + i;
        int qc = q < p1 ? q : p1 - 1;
        rr[i] = (unsigned)perm[qc];
        mk[i] = (q < p1) ? 1.0f : 0.0f;
      }
#pragma unroll
      for (int i = 0; i < 16; ++i) ee[i] = e[rr[i]];
#pragma unroll
      for (int i = 0; i < 16; ++i) ww[i] = bf16dec(Wh[(size_t)rr[i] * OUT_CH + lane]);
#pragma unroll
      for (int i = 0; i < 16; ++i) {
        float v = __expf(ee[i] + ec) * mk[i];
        if ((i & 3) == 0) { a0 = fmaf(v, ww[i], a0); s0 += v; }
        else if ((i & 3) == 1) { a1 = fmaf(v, ww[i], a1); s1 += v; }
        else if ((i & 3) == 2) { a2 = fmaf(v, ww[i], a2); s2 += v; }
        else { a3 = fmaf(v, ww[i], a3); s3 += v; }
      }
    }
  }
  float acc = (a0 + a1) + (a2 + a3);
  float ssum = (s0 + s1) + (s2 + s3);
  float rden = (p1 > p0) ? 1.0f / ssum : 0.0f;  // empty segment -> elu(0)=0
  acc *= rden;
  out[(size_t)c * OUT_CH + lane] = acc > 0.f ? acc : expm1f(acc);
}

extern "C" void kernel_launch(void* const* d_in, const int* in_sizes, int n_in,
                              void* d_out, int out_size, void* d_ws, size_t ws_size,
                              hipStream_t stream)
{
  const float* x     = (const float*)d_in[0];
  const void*  eidx  = d_in[1];
  const float* W     = (const float*)d_in[2];
  const float* a_src = (const float*)d_in[3];
  const float* a_dst = (const float*)d_in[4];
  float* out = (float*)d_out;

  const int n = in_sizes[0] / IN_CH;   // 50000
  const int E = in_sizes[1] / 2;       // 800000
  const int nb = (n + SCHUNK - 1) / SCHUNK;

  char* ws = (char*)d_ws;
  size_t off = 0;
  auto alloc = [&](size_t bytes) -> void* {
    void* p = ws + off;
    off = (off + bytes + 255) & ~(size_t)255;
    return p;
  };
  ushort*   Wh     = (ushort*)alloc((size_t)n * OUT_CH * 2);   // bf16
  float*    e      = (float*)alloc((size_t)n * 4);
  void*     perm   = alloc((size_t)E * 4);   // ushort or uint, by n
  void*     rcbuf  = alloc((size_t)E * 8);   // packed u32 or uint2, by n
  void*     rank   = alloc((size_t)E * 4);   // u16 or u32, by n
  int*      cnt    = (int*)alloc((size_t)n * 4);
  int*      segp   = (int*)alloc((size_t)(n + 1) * 4);
  int*      bsum   = (int*)alloc((size_t)nb * 4);
  ushort*   Whi    = (ushort*)alloc((size_t)IN_CH * OUT_CH * 2);
  ushort*   Wlo    = (ushort*)alloc((size_t)IN_CH * OUT_CH * 2);
  unsigned* gmax   = (unsigned*)alloc(4);
  unsigned* flag   = (unsigned*)alloc(4);

  int prep_blocks = (n + 255) / 256;
  if (prep_blocks < 65) prep_blocks = 65;
  gat_prep<<<prep_blocks, 256, 0, stream>>>(
      W, Whi, Wlo, (const unsigned*)eidx, flag, cnt, gmax, n, 8192);
  gat_gemm_mfma<<<(n + 31) / 32, 512, 0, stream>>>(x, Whi, Wlo, a_src, a_dst, Wh, e, gmax, n);

  if (n <= 65536) {
    gat_pass1<ushort><<<(E + 255) / 256, 256, 0, stream>>>(
        eidx, flag, cnt, rcbuf, (ushort*)rank, E);
  } else {
    gat_pass1<unsigned><<<(E + 255) / 256, 256, 0, stream>>>(
        eidx, flag, cnt, rcbuf, (unsigned*)rank, E);
  }
  scan_partial<<<nb, 256, 0, stream>>>(cnt, bsum, n);
  scan_bsum<<<1, 256, 0, stream>>>(bsum, segp, nb, n, E);
  scan_final<<<nb, 256, 0, stream>>>(cnt, bsum, segp, n);
  if (n <= 65536) {
    gat_scatter<ushort><<<(E + 255) / 256, 256, 0, stream>>>(
        rcbuf, (const ushort*)rank, segp, (ushort*)perm, E);
    gat_aggregate<ushort><<<(n + 3) / 4, 256, 0, stream>>>(
        Wh, e, gmax, (const ushort*)perm, segp, out, n);
  } else {
    gat_scatter<unsigned><<<(E + 255) / 256, 256, 0, stream>>>(
        rcbuf, (const unsigned*)rank, segp, (unsigned*)perm, E);
    gat_aggregate<unsigned><<<(n + 3) / 4, 256, 0, stream>>>(
        Wh, e, gmax, (const unsigned*)perm, segp, out, n);
  }
}

// Round 18
// 126.556 us; speedup vs baseline: 1.2610x; 1.0462x over previous
//
#include <hip/hip_runtime.h>
#include <math.h>

#define IN_CH 256
#define OUT_CH 64
#define SCHUNK 512  // scan elements per block (needs n <= 256*SCHUNK = 131072)

typedef unsigned short ushort;
typedef unsigned short ushort8 __attribute__((ext_vector_type(8)));
typedef unsigned int uint32x4 __attribute__((ext_vector_type(4)));
typedef __bf16 bf16x8 __attribute__((ext_vector_type(8)));
typedef float f32x4 __attribute__((ext_vector_type(4)));

// ---------- monotonic float<->uint mapping for atomic max ----------
__device__ __forceinline__ unsigned fmap(float f) {
  unsigned u = __float_as_uint(f);
  return (u & 0x80000000u) ? ~u : (u | 0x80000000u);
}
__device__ __forceinline__ float funmap(unsigned u) {
  return (u & 0x80000000u) ? __uint_as_float(u & 0x7fffffffu) : __uint_as_float(~u);
}

__device__ __forceinline__ ushort bf16rne(float v) {
  unsigned u = __float_as_uint(v);
  return (ushort)((u + 0x7FFFu + ((u >> 16) & 1u)) >> 16);
}
__device__ __forceinline__ float bf16dec(ushort h) {
  return __uint_as_float((unsigned)h << 16);
}

// ---------- K0: fused prep — cnt clear + gmax clear + int64 detect + W split ----------
__global__ __launch_bounds__(256) void gat_prep(
    const float* __restrict__ W, ushort* __restrict__ Whi, ushort* __restrict__ Wlo,
    const unsigned* __restrict__ eidx, unsigned* __restrict__ flag,
    int* __restrict__ cnt, unsigned* __restrict__ gmax, int n, int npairs)
{
  __shared__ unsigned wsh[4];
  const int b = blockIdx.x, tid = threadIdx.x;
  const int i = b * 256 + tid;
  if (i < n) cnt[i] = 0;
  if (i == 0) *gmax = 0u;
  if (b == 0) {
    unsigned v = 0;
    for (int k = tid; k < npairs; k += 256) v |= eidx[2 * k + 1];
#pragma unroll
    for (int m = 1; m < 64; m <<= 1) v |= __shfl_xor(v, m);
    if ((tid & 63) == 0) wsh[tid >> 6] = v;
    __syncthreads();
    if (tid == 0) *flag = wsh[0] | wsh[1] | wsh[2] | wsh[3];
  } else if (b <= 64) {
    int j = (b - 1) * 256 + tid;                   // 0..16383
    int e = j & 7, ln = (j >> 3) & 63, ctks = j >> 9;
    int ct = ctks & 3, ks = ctks >> 2;
    int k = ks * 32 + (ln >> 4) * 8 + e;
    int col = ct * 16 + (ln & 15);
    float v = W[(size_t)k * OUT_CH + col];
    unsigned u = __float_as_uint(v);
    unsigned hb = u & 0xFFFF0000u;                 // truncation split (lo absorbs error)
    Whi[j] = (ushort)(hb >> 16);
    Wlo[j] = bf16rne(v - __uint_as_float(hb));
  }
}

// ---------- K1: Wh = x @ W via split-bf16 MFMA, 32-row blocks, 2 blocks/CU ----------
__global__ __launch_bounds__(512, 4) void gat_gemm_mfma(
    const float* __restrict__ x, const ushort* __restrict__ Whi, const ushort* __restrict__ Wlo,
    const float* __restrict__ a_src, const float* __restrict__ a_dst,
    ushort* __restrict__ Wh, float* __restrict__ e, unsigned* __restrict__ gmax, int n)
{
  __shared__ __align__(16) ushort Af[2 * 8 * 2 * 64 * 8];  // 32KB [hl][ks][rg][lane][e]
  __shared__ uint4  Wl[2048];                              // 32KB Wlo frags (full)
  const int tid = threadIdx.x;
  const int lane = tid & 63;
  const int wave = tid >> 6;
  const int ct = wave & 3;             // column tile
  const int rg = wave >> 2;            // row group (0/1)
  const int lg = lane >> 4;            // k-pack group
  const int li = lane & 15;            // row (A) / col (B/D)
  const int row0 = blockIdx.x * 32;

  // stage Wlo fragments (2048 uint4 / 512 threads)
#pragma unroll
  for (int i = 0; i < 4; ++i) Wl[tid + i * 512] = ((const uint4*)Wlo)[tid + i * 512];

  // my ct's Whi fragments: 32 VGPRs (L2-hot)
  bf16x8 wh[8];
#pragma unroll
  for (int ks = 0; ks < 8; ++ks)
    wh[ks] = __builtin_bit_cast(bf16x8, ((const uint4*)Whi)[(ks * 4 + ct) * 64 + lane]);

  // stage x tile: thread = (row = tid>>4 in 0..31, kq = tid&15); 4 passes x float4
  {
    const int row = tid >> 4, kq = tid & 15;
    const int xrg = row >> 4, r16 = row & 15;
    int arow = row0 + row; if (arow > n - 1) arow = n - 1;
    const float* __restrict__ xr = x + (size_t)arow * IN_CH;
#pragma unroll
    for (int p = 0; p < 4; ++p) {
      const int c0 = (p * 16 + kq) * 4;
      float4 v = *(const float4*)(xr + c0);
      unsigned b0 = __float_as_uint(v.x), b1 = __float_as_uint(v.y);
      unsigned b2 = __float_as_uint(v.z), b3 = __float_as_uint(v.w);
      uint2 hi = { (b1 & 0xFFFF0000u) | (b0 >> 16),
                   (b3 & 0xFFFF0000u) | (b2 >> 16) };
      float l0 = v.x - __uint_as_float(b0 & 0xFFFF0000u);
      float l1 = v.y - __uint_as_float(b1 & 0xFFFF0000u);
      float l2 = v.z - __uint_as_float(b2 & 0xFFFF0000u);
      float l3 = v.w - __uint_as_float(b3 & 0xFFFF0000u);
      uint2 lo = { ((unsigned)bf16rne(l1) << 16) | bf16rne(l0),
                   ((unsigned)bf16rne(l3) << 16) | bf16rne(l2) };
      const int ks = c0 >> 5;
      const int ln = ((c0 >> 3) & 3) * 16 + r16;
      const int e0 = c0 & 7;               // 0 or 4
      *(uint2*)&Af[(((0 * 8 + ks) * 2 + xrg) * 64 + ln) * 8 + e0] = hi;
      *(uint2*)&Af[(((1 * 8 + ks) * 2 + xrg) * 64 + ln) * 8 + e0] = lo;
    }
  }

  const int col = ct * 16 + li;
  const float asd = a_src[col] + a_dst[col];
  __syncthreads();

  // K-loop: pure LDS reads + MFMA
  f32x4 acc = {0.f, 0.f, 0.f, 0.f};
#pragma unroll
  for (int ks = 0; ks < 8; ++ks) {
    bf16x8 ah = __builtin_bit_cast(bf16x8, ((const uint4*)Af)[((0 * 8 + ks) * 2 + rg) * 64 + lane]);
    bf16x8 al = __builtin_bit_cast(bf16x8, ((const uint4*)Af)[((1 * 8 + ks) * 2 + rg) * 64 + lane]);
    bf16x8 wl = __builtin_bit_cast(bf16x8, Wl[(ks * 4 + ct) * 64 + lane]);
    acc = __builtin_amdgcn_mfma_f32_16x16x32_bf16(ah, wh[ks], acc, 0, 0, 0);
    acc = __builtin_amdgcn_mfma_f32_16x16x32_bf16(al, wh[ks], acc, 0, 0, 0);
    acc = __builtin_amdgcn_mfma_f32_16x16x32_bf16(ah, wl, acc, 0, 0, 0);
    acc = __builtin_amdgcn_mfma_f32_16x16x32_bf16(al, wl, acc, 0, 0, 0);
  }

  // store Wh as bf16 (D: row = rg*16 + lg*4 + r, col)
#pragma unroll
  for (int r = 0; r < 4; ++r) {
    int row = row0 + rg * 16 + lg * 4 + r;
    if (row < n) Wh[(size_t)row * OUT_CH + col] = bf16rne(acc[r]);
  }

  __syncthreads();                      // A-frag reads done; reuse Af as ep
  float* ep = (float*)Af;               // ep[ct*32 + rg*16 + local]

  // per-ct e partials: reduce over this wave's 16 cols
#pragma unroll
  for (int r = 0; r < 4; ++r) {
    float pe = acc[r] * asd;
    pe += __shfl_xor(pe, 1); pe += __shfl_xor(pe, 2);
    pe += __shfl_xor(pe, 4); pe += __shfl_xor(pe, 8);
    if (li == 0) ep[ct * 32 + rg * 16 + lg * 4 + r] = pe;   // lanes 0,16,32,48
  }
  __syncthreads();

  // lanes 0..31 of wave 0: sum 4 ct partials, write e, track max
  if (tid < 32) {
    int row = row0 + tid;
    float pe = ep[0 * 32 + tid] + ep[1 * 32 + tid] + ep[2 * 32 + tid] + ep[3 * 32 + tid];
    float vmax = -INFINITY;
    if (row < n) { e[row] = pe; vmax = pe; }
    vmax = fmaxf(vmax, __shfl_xor(vmax, 1));
    vmax = fmaxf(vmax, __shfl_xor(vmax, 2));
    vmax = fmaxf(vmax, __shfl_xor(vmax, 4));
    vmax = fmaxf(vmax, __shfl_xor(vmax, 8));
    vmax = fmaxf(vmax, __shfl_xor(vmax, 16));
    if (tid == 0) atomicMax(gmax, fmap(vmax));
  }
}

// ---------- K3: decode edges, count degrees, emit packed rc + rank; also q[j]=exp(e[j]-gmax) ----------
template <typename IDX>
__global__ void gat_pass1(
    const void* __restrict__ eidx, const unsigned* __restrict__ flag,
    int* __restrict__ cnt, void* __restrict__ rcbuf, IDX* __restrict__ rank,
    const float* __restrict__ e, const unsigned* __restrict__ gmax,
    float* __restrict__ q, int n, int E)
{
  int j = blockIdx.x * blockDim.x + threadIdx.x;
  if (j >= E) return;
  if (j < n) q[j] = __expf(e[j] - funmap(*gmax));   // factorized softmax weight, <= 1
  int r, c;
  if (*flag == 0) {  // int64 layout
    const long long* p = (const long long*)eidx;
    r = (int)p[j]; c = (int)p[(size_t)E + j];
  } else {           // int32 layout
    const int* p = (const int*)eidx;
    r = p[j]; c = p[(size_t)E + j];
  }
  int rk = atomicAdd(cnt + c, 1);
  if constexpr (sizeof(IDX) == 2) {
    ((unsigned*)rcbuf)[j] = ((unsigned)c << 16) | (unsigned)r;
  } else {
    ((uint2*)rcbuf)[j] = make_uint2((unsigned)r, (unsigned)c);
  }
  rank[j] = (IDX)rk;
}

// ---------- K4a/b/c: hierarchical exclusive scan of cnt -> segp ----------
__global__ __launch_bounds__(256) void scan_partial(
    const int* __restrict__ cnt, int* __restrict__ bsum, int n)
{
  int base = blockIdx.x * SCHUNK;
  int tid = threadIdx.x;
  int s = 0;
  int i0 = base + tid, i1 = base + tid + 256;
  if (i0 < n) s += cnt[i0];
  if (i1 < n) s += cnt[i1];
#pragma unroll
  for (int m = 1; m < 64; m <<= 1) s += __shfl_xor(s, m);
  __shared__ int ws[4];
  if ((tid & 63) == 0) ws[tid >> 6] = s;
  __syncthreads();
  if (tid == 0) bsum[blockIdx.x] = ws[0] + ws[1] + ws[2] + ws[3];
}

__global__ __launch_bounds__(256) void scan_bsum(
    int* __restrict__ bsum, int* __restrict__ segp, int nb, int n, int E)
{
  __shared__ int sh[256];
  int tid = threadIdx.x;
  int v = (tid < nb) ? bsum[tid] : 0;
  sh[tid] = v;
  __syncthreads();
  for (int off = 1; off < 256; off <<= 1) {
    int add = (tid >= off) ? sh[tid - off] : 0;
    __syncthreads();
    sh[tid] += add;
    __syncthreads();
  }
  if (tid < nb) bsum[tid] = sh[tid] - v;   // exclusive block offsets
  if (tid == 0) segp[n] = E;
}

__global__ __launch_bounds__(256) void scan_final(
    const int* __restrict__ cnt, const int* __restrict__ bsum,
    int* __restrict__ segp, int n)
{
  int base = blockIdx.x * SCHUNK;
  int tid = threadIdx.x;
  int i0 = base + 2 * tid, i1 = i0 + 1;
  int c0 = (i0 < n) ? cnt[i0] : 0;
  int c1 = (i1 < n) ? cnt[i1] : 0;
  int ps = c0 + c1;
  __shared__ int sh[256];
  sh[tid] = ps;
  __syncthreads();
  for (int off = 1; off < 256; off <<= 1) {
    int add = (tid >= off) ? sh[tid - off] : 0;
    __syncthreads();
    sh[tid] += add;
    __syncthreads();
  }
  int excl = sh[tid] - ps + bsum[blockIdx.x];
  if (i0 < n) segp[i0] = excl;
  if (i1 < n) segp[i1] = excl + c0;
}

// ---------- K5: atomic-free CSR scatter: perm[segp[c]+rank] = r ----------
template <typename IDX>
__global__ void gat_scatter(
    const void* __restrict__ rcbuf, const IDX* __restrict__ rank,
    const int* __restrict__ segp, IDX* __restrict__ perm, int E)
{
  int j = blockIdx.x * blockDim.x + threadIdx.x;
  if (j >= E) return;
  unsigned r, c;
  if constexpr (sizeof(IDX) == 2) {
    unsigned p = ((const unsigned*)rcbuf)[j];
    r = p & 0xFFFFu; c = p >> 16;
  } else {
    uint2 p = ((const uint2*)rcbuf)[j];
    r = p.x; c = p.y;
  }
  perm[segp[c] + (int)rank[j]] = (IDX)r;
}

// ---------- K6: aggregate + ELU; factorized softmax (no exp in loop), scalarized gathers ----------
// out_c = sum_r q[r]*Wh[r] / sum_r q[r]  — the q[c] factor cancels analytically.
// perm[p] is wave-uniform -> readfirstlane puts row in SGPR: q = s_load, Wh addr = SALU base + lane*2.
template <typename IDX>
__global__ __launch_bounds__(256) void gat_aggregate(
    const ushort* __restrict__ Wh, const float* __restrict__ q,
    const IDX* __restrict__ perm, const int* __restrict__ segp,
    float* __restrict__ out, int n)
{
  int wave = threadIdx.x >> 6, lane = threadIdx.x & 63;
  int c = blockIdx.x * 4 + wave;
  if (c >= n) return;
  int p0 = segp[c], p1 = segp[c + 1];

  float a0 = 0.f, a1 = 0.f, a2 = 0.f, a3 = 0.f;
  float d0 = 0.f, d1 = 0.f, d2 = 0.f, d3 = 0.f;
  int p = p0;
  for (; p + 8 <= p1; p += 8) {
    int r0 = __builtin_amdgcn_readfirstlane((int)perm[p]);
    int r1 = __builtin_amdgcn_readfirstlane((int)perm[p + 1]);
    int r2 = __builtin_amdgcn_readfirstlane((int)perm[p + 2]);
    int r3 = __builtin_amdgcn_readfirstlane((int)perm[p + 3]);
    int r4 = __builtin_amdgcn_readfirstlane((int)perm[p + 4]);
    int r5 = __builtin_amdgcn_readfirstlane((int)perm[p + 5]);
    int r6 = __builtin_amdgcn_readfirstlane((int)perm[p + 6]);
    int r7 = __builtin_amdgcn_readfirstlane((int)perm[p + 7]);
    float q0 = q[r0], q1 = q[r1], q2 = q[r2], q3 = q[r3];
    float q4 = q[r4], q5 = q[r5], q6 = q[r6], q7 = q[r7];
    float w0 = bf16dec(Wh[(size_t)r0 * OUT_CH + lane]);
    float w1 = bf16dec(Wh[(size_t)r1 * OUT_CH + lane]);
    float w2 = bf16dec(Wh[(size_t)r2 * OUT_CH + lane]);
    float w3 = bf16dec(Wh[(size_t)r3 * OUT_CH + lane]);
    float w4 = bf16dec(Wh[(size_t)r4 * OUT_CH + lane]);
    float w5 = bf16dec(Wh[(size_t)r5 * OUT_CH + lane]);
    float w6 = bf16dec(Wh[(size_t)r6 * OUT_CH + lane]);
    float w7 = bf16dec(Wh[(size_t)r7 * OUT_CH + lane]);
    a0 = fmaf(q0, w0, a0); d0 += q0;
    a1 = fmaf(q1, w1, a1); d1 += q1;
    a2 = fmaf(q2, w2, a2); d2 += q2;
    a3 = fmaf(q3, w3, a3); d3 += q3;
    a0 = fmaf(q4, w4, a0); d0 += q4;
    a1 = fmaf(q5, w5, a1); d1 += q5;
    a2 = fmaf(q6, w6, a2); d2 += q6;
    a3 = fmaf(q7, w7, a3); d3 += q7;
  }
  for (; p < p1; ++p) {
    int r = __builtin_amdgcn_readfirstlane((int)perm[p]);
    float qq = q[r];
    a0 = fmaf(qq, bf16dec(Wh[(size_t)r * OUT_CH + lane]), a0); d0 += qq;
  }
  float acc = (a0 + a1) + (a2 + a3);
  float den = (d0 + d1) + (d2 + d3);
  float rden = (p1 > p0) ? 1.0f / den : 0.0f;  // empty segment -> elu(0)=0
  acc *= rden;
  out[(size_t)c * OUT_CH + lane] = acc > 0.f ? acc : expm1f(acc);
}

extern "C" void kernel_launch(void* const* d_in, const int* in_sizes, int n_in,
                              void* d_out, int out_size, void* d_ws, size_t ws_size,
                              hipStream_t stream)
{
  const float* x     = (const float*)d_in[0];
  const void*  eidx  = d_in[1];
  const float* W     = (const float*)d_in[2];
  const float* a_src = (const float*)d_in[3];
  const float* a_dst = (const float*)d_in[4];
  float* out = (float*)d_out;

  const int n = in_sizes[0] / IN_CH;   // 50000
  const int E = in_sizes[1] / 2;       // 800000
  const int nb = (n + SCHUNK - 1) / SCHUNK;

  char* ws = (char*)d_ws;
  size_t off = 0;
  auto alloc = [&](size_t bytes) -> void* {
    void* p = ws + off;
    off = (off + bytes + 255) & ~(size_t)255;
    return p;
  };
  ushort*   Wh     = (ushort*)alloc((size_t)n * OUT_CH * 2);   // bf16
  float*    e      = (float*)alloc((size_t)n * 4);
  float*    q      = (float*)alloc((size_t)n * 4);
  void*     perm   = alloc((size_t)E * 4);   // ushort or uint, by n
  void*     rcbuf  = alloc((size_t)E * 8);   // packed u32 or uint2, by n
  void*     rank   = alloc((size_t)E * 4);   // u16 or u32, by n
  int*      cnt    = (int*)alloc((size_t)n * 4);
  int*      segp   = (int*)alloc((size_t)(n + 1) * 4);
  int*      bsum   = (int*)alloc((size_t)nb * 4);
  ushort*   Whi    = (ushort*)alloc((size_t)IN_CH * OUT_CH * 2);
  ushort*   Wlo    = (ushort*)alloc((size_t)IN_CH * OUT_CH * 2);
  unsigned* gmax   = (unsigned*)alloc(4);
  unsigned* flag   = (unsigned*)alloc(4);

  int prep_blocks = (n + 255) / 256;
  if (prep_blocks < 65) prep_blocks = 65;
  gat_prep<<<prep_blocks, 256, 0, stream>>>(
      W, Whi, Wlo, (const unsigned*)eidx, flag, cnt, gmax, n, 8192);
  gat_gemm_mfma<<<(n + 31) / 32, 512, 0, stream>>>(x, Whi, Wlo, a_src, a_dst, Wh, e, gmax, n);

  if (n <= 65536) {
    gat_pass1<ushort><<<(E + 255) / 256, 256, 0, stream>>>(
        eidx, flag, cnt, rcbuf, (ushort*)rank, e, gmax, q, n, E);
  } else {
    gat_pass1<unsigned><<<(E + 255) / 256, 256, 0, stream>>>(
        eidx, flag, cnt, rcbuf, (unsigned*)rank, e, gmax, q, n, E);
  }
  scan_partial<<<nb, 256, 0, stream>>>(cnt, bsum, n);
  scan_bsum<<<1, 256, 0, stream>>>(bsum, segp, nb, n, E);
  scan_final<<<nb, 256, 0, stream>>>(cnt, bsum, segp, n);
  if (n <= 65536) {
    gat_scatter<ushort><<<(E + 255) / 256, 256, 0, stream>>>(
        rcbuf, (const ushort*)rank, segp, (ushort*)perm, E);
    gat_aggregate<ushort><<<(n + 3) / 4, 256, 0, stream>>>(
        Wh, q, (const ushort*)perm, segp, out, n);
  } else {
    gat_scatter<unsigned><<<(E + 255) / 256, 256, 0, stream>>>(
        rcbuf, (const unsigned*)rank, segp, (unsigned*)perm, E);
    gat_aggregate<unsigned><<<(n + 3) / 4, 256, 0, stream>>>(
        Wh, q, (const unsigned*)perm, segp, out, n);
  }
}